// Round 2
// baseline (3025.666 us; speedup 1.0000x reference)
//
#include <hip/hip_runtime.h>
#include <math.h>

#define B_ 2
#define L_ 2048
#define DM 1024
#define DS 128
#define DI 2048
#define NH 32
#define CONVD 2304
#define DIP 4384
#define NPAD 4480
#define EPS_ 1e-5f

typedef __attribute__((ext_vector_type(8))) short bf16x8;
typedef __attribute__((ext_vector_type(4))) float f32x4;

__device__ __forceinline__ float silu_f(float x) { return x / (1.0f + __expf(-x)); }

__device__ __forceinline__ unsigned short f2bf(float x) {
    union { float f; unsigned u; } v; v.f = x;
    unsigned r = v.u + 0x7fffu + ((v.u >> 16) & 1u);
    return (unsigned short)(r >> 16);
}

// async global->LDS, 16B per lane; lds base must be wave-uniform (lane*16 implicit)
__device__ __forceinline__ void gload_lds16(const unsigned short* g, unsigned short* l) {
    __builtin_amdgcn_global_load_lds(
        (const __attribute__((address_space(1))) unsigned int*)g,
        (__attribute__((address_space(3))) unsigned int*)l, 16, 0, 0);
}

// ---------------- fp32 -> bf16 cast with optional zero tail-pad ----------------
__global__ __launch_bounds__(256) void castpad_kernel(
    const float* __restrict__ src, unsigned short* __restrict__ dst, int n_src, int n_dst)
{
    int i = (blockIdx.x * 256 + threadIdx.x) * 4;
    if (i >= n_dst) return;
    ushort4 o;
    if (i < n_src) {
        float4 v = *(const float4*)(src + i);
        o = make_ushort4(f2bf(v.x), f2bf(v.y), f2bf(v.z), f2bf(v.w));
    } else {
        o = make_ushort4(0, 0, 0, 0);
    }
    *(ushort4*)(dst + i) = o;
}

// ---------------- rmsnorm over 1024 cols, bf16 out ----------------
__global__ __launch_bounds__(256) void rmsnorm_kernel(
    const float* __restrict__ x, const float* __restrict__ w, unsigned short* __restrict__ out)
{
    int row = blockIdx.x;
    int t = threadIdx.x;
    const float4* xr = (const float4*)(x + (size_t)row * DM);
    float4 v = xr[t];
    float ss = v.x*v.x + v.y*v.y + v.z*v.z + v.w*v.w;
#pragma unroll
    for (int o = 32; o > 0; o >>= 1) ss += __shfl_down(ss, o, 64);
    __shared__ float red[4];
    if ((t & 63) == 0) red[t >> 6] = ss;
    __syncthreads();
    float tot = red[0] + red[1] + red[2] + red[3];
    float inv = rsqrtf(tot * (1.0f / DM) + EPS_);
    float4 wv = ((const float4*)w)[t];
    ushort4 o4 = make_ushort4(f2bf(v.x * inv * wv.x), f2bf(v.y * inv * wv.y),
                              f2bf(v.z * inv * wv.z), f2bf(v.w * inv * wv.w));
    ((ushort4*)(out + (size_t)row * DM))[t] = o4;
}

// ---------------- bf16 MFMA GEMM: C(f32) = A(MxK,bf16) * Wt(NxK,bf16)^T ----------------
// 128x128 tile, BK=32, 4 waves each owning a 64x64 quadrant (4x4 frags of 16x16x32).
// m97 structure: global_load_lds(16B) staging, 2 barriers/K-step.
// flipA/flipOut remap rows l -> L-1-l within each batch (L=2048 pow2 -> xor 2047).
__global__ __launch_bounds__(256, 2) void gemm_bf16_kernel(
    const unsigned short* __restrict__ A, const unsigned short* __restrict__ Wt,
    float* __restrict__ C, const float* __restrict__ bias, const float* __restrict__ resid,
    int M, int N, int K, int ldc, int col_off, int flipA, int flipOut)
{
    __shared__ unsigned short As[128 * 32];
    __shared__ unsigned short Bs[128 * 32];
    const int tid = threadIdx.x;
    const int lane = tid & 63, wave = tid >> 6;
    const int wr = wave >> 1, wc = wave & 1;
    const int r16 = lane & 15, kg = lane >> 4;
    const int bn0 = blockIdx.x * 128;
    const int bm0 = blockIdx.y * 128;

    f32x4 acc[4][4];
#pragma unroll
    for (int m = 0; m < 4; ++m)
#pragma unroll
        for (int n = 0; n < 4; ++n) { f32x4 z = {0.f, 0.f, 0.f, 0.f}; acc[m][n] = z; }

    for (int k0 = 0; k0 < K; k0 += 32) {
#pragma unroll
        for (int i = 0; i < 2; ++i) {
            int c = wave * 128 + i * 64 + lane;   // chunk 0..511: r=c>>2, kgrp=c&3
            int r = c >> 2;
            int kk = (c & 3) << 3;
            int gr = bm0 + r;
            if (flipA) gr ^= (L_ - 1);
            gload_lds16(A + (size_t)gr * K + k0 + kk, As + (size_t)(wave * 128 + i * 64) * 8);
            gload_lds16(Wt + (size_t)(bn0 + r) * K + k0 + kk, Bs + (size_t)(wave * 128 + i * 64) * 8);
        }
        __syncthreads();
        bf16x8 af[4], bfr[4];
        const bf16x8* Ap = (const bf16x8*)As;
        const bf16x8* Bp = (const bf16x8*)Bs;
#pragma unroll
        for (int m = 0; m < 4; ++m) af[m] = Ap[(wr * 64 + m * 16 + r16) * 4 + kg];
#pragma unroll
        for (int n = 0; n < 4; ++n) bfr[n] = Bp[(wc * 64 + n * 16 + r16) * 4 + kg];
#pragma unroll
        for (int m = 0; m < 4; ++m)
#pragma unroll
            for (int n = 0; n < 4; ++n)
                acc[m][n] = __builtin_amdgcn_mfma_f32_16x16x32_bf16(af[m], bfr[n], acc[m][n], 0, 0, 0);
        __syncthreads();
    }

    // C/D frag map (m89-verified): col = lane&15, row = (lane>>4)*4 + reg
#pragma unroll
    for (int m = 0; m < 4; ++m) {
        int row = bm0 + wr * 64 + m * 16 + kg * 4;
#pragma unroll
        for (int n = 0; n < 4; ++n) {
            int col = bn0 + wc * 64 + n * 16 + r16;
            if (col < N) {
                float bv = bias ? bias[col] : 0.f;
#pragma unroll
                for (int j = 0; j < 4; ++j) {
                    int ro = flipOut ? ((row + j) ^ (L_ - 1)) : (row + j);
                    size_t o = (size_t)ro * ldc + col_off + col;
                    float val = acc[m][n][j] + bv;
                    if (resid) val += resid[o];
                    C[o] = val;
                }
            }
        }
    }
}

// ---------------- causal depthwise conv(4) + silu + dt/dA ----------------
__global__ __launch_bounds__(256) void convdt_kernel(
    const float* __restrict__ zx, const float* __restrict__ conv_w,
    const float* __restrict__ conv_b, const float* __restrict__ dt_bias,
    const float* __restrict__ A_log, const float* __restrict__ Dskip,
    float* __restrict__ xs, float* __restrict__ bc,
    float* __restrict__ dtb, float* __restrict__ dab, float* __restrict__ ys)
{
    int row = blockIdx.x;          // b*L + l
    int l = row & (L_ - 1);
    int t = threadIdx.x;
#pragma unroll
    for (int cc = 0; cc < 9; ++cc) {
        int c = t + cc * 256;      // CONVD = 2304 = 9*256
        float acc = conv_b[c];
#pragma unroll
        for (int k = 0; k < 4; ++k) {
            int ll = l - 3 + k;
            if (ll >= 0)
                acc = fmaf(conv_w[c * 4 + k], zx[(size_t)(row - 3 + k) * DIP + DI + c], acc);
        }
        float v = silu_f(acc);
        if (c < DI) {
            xs[(size_t)row * DI + c] = v;
            ys[(size_t)row * DI + c] = Dskip[c >> 6] * v;   // init y with D-skip term
        } else {
            bc[(size_t)row * (2 * DS) + (c - DI)] = v;
        }
    }
    if (t < NH) {
        float xv = zx[(size_t)row * DIP + DI + CONVD + t] + dt_bias[t];
        float dt = (xv > 20.f) ? xv : log1pf(__expf(xv));
        float a = -__expf(A_log[t]);
        dtb[row * NH + t] = dt;
        dab[row * NH + t] = __expf(dt * a);
    }
}

// ---------------- selective scan: grid (64 bh, 4 state-chunks) ----------------
__global__ __launch_bounds__(256) void scan_kernel(
    const float* __restrict__ xs, const float* __restrict__ bc,
    const float* __restrict__ dtb, const float* __restrict__ dab,
    float* __restrict__ ys)
{
    int bh = blockIdx.x;            // 0..63
    int chunk = blockIdx.y;         // 0..3
    int b = bh >> 5, h = bh & 31;
    int t = threadIdx.x;
    int p = t >> 2, q = t & 3;
    float s[8];
#pragma unroll
    for (int j = 0; j < 8; ++j) s[j] = 0.f;
    __shared__ float sb[2][132];    // [0,32)=B  [32,64)=C  [64,128)=x  [128]=dt [129]=dA

    const float* ptr = nullptr;
    size_t stride = 0;
    size_t rowbase = (size_t)b * L_;
    if (t < 64) {
        int off = (t < 32) ? (chunk * 32 + t) : (128 + chunk * 32 + (t - 32));
        ptr = bc + rowbase * (2 * DS) + off; stride = 2 * DS;
    } else if (t < 128) {
        ptr = xs + rowbase * DI + h * 64 + (t - 64); stride = DI;
    } else if (t == 128) { ptr = dtb + rowbase * NH + h; stride = NH; }
    else if (t == 129)   { ptr = dab + rowbase * NH + h; stride = NH; }

    float pre = ptr ? ptr[0] : 0.f;
    for (int l = 0; l < L_; ++l) {
        int pb = l & 1;
        if (t < 130) sb[pb][t] = pre;
        if (t < 130 && l + 1 < L_) pre = ptr[(size_t)(l + 1) * stride];  // prefetch next row
        __syncthreads();
        float dtv = sb[pb][128];
        float dav = sb[pb][129];
        float xv  = sb[pb][64 + p];
        float dtx = dtv * xv;
        const float* Bp = &sb[pb][q * 8];
        const float* Cp = &sb[pb][32 + q * 8];
        float acc = 0.f;
#pragma unroll
        for (int j = 0; j < 8; ++j) {
            s[j] = fmaf(s[j], dav, dtx * Bp[j]);
            acc  = fmaf(s[j], Cp[j], acc);
        }
        acc += __shfl_xor(acc, 1, 64);
        acc += __shfl_xor(acc, 2, 64);
        if (q == 0) atomicAdd(&ys[(rowbase + l) * DI + h * 64 + p], acc);
    }
}

// ---------------- gate: u = rmsnorm(y * silu(z)) * norm_w, bf16 out ----------------
__global__ __launch_bounds__(256) void gate_kernel(
    const float* __restrict__ ys, const float* __restrict__ zx,
    const float* __restrict__ nw, unsigned short* __restrict__ u)
{
    int row = blockIdx.x;
    int t = threadIdx.x;
    const float4* yr = (const float4*)(ys + (size_t)row * DI);
    const float4* zr = (const float4*)(zx + (size_t)row * DIP);   // z = cols [0,2048)
    float g[2][4];
    float ss = 0.f;
#pragma unroll
    for (int it = 0; it < 2; ++it) {
        int i = t + it * 256;
        float4 y4 = yr[i];
        float4 z4 = zr[i];
        float gv;
        gv = y4.x * silu_f(z4.x); g[it][0] = gv; ss += gv * gv;
        gv = y4.y * silu_f(z4.y); g[it][1] = gv; ss += gv * gv;
        gv = y4.z * silu_f(z4.z); g[it][2] = gv; ss += gv * gv;
        gv = y4.w * silu_f(z4.w); g[it][3] = gv; ss += gv * gv;
    }
#pragma unroll
    for (int o = 32; o > 0; o >>= 1) ss += __shfl_down(ss, o, 64);
    __shared__ float red[4];
    if ((t & 63) == 0) red[t >> 6] = ss;
    __syncthreads();
    float tot = red[0] + red[1] + red[2] + red[3];
    float inv = rsqrtf(tot * (1.0f / DI) + EPS_);
#pragma unroll
    for (int it = 0; it < 2; ++it) {
        int i = t + it * 256;
        float4 w4 = ((const float4*)nw)[i];
        ushort4 o4 = make_ushort4(f2bf(g[it][0] * inv * w4.x), f2bf(g[it][1] * inv * w4.y),
                                  f2bf(g[it][2] * inv * w4.z), f2bf(g[it][3] * inv * w4.w));
        ((ushort4*)(u + (size_t)row * DI))[i] = o4;
    }
}

extern "C" void kernel_launch(void* const* d_in, const int* in_sizes, int n_in,
                              void* d_out, int out_size, void* d_ws, size_t ws_size,
                              hipStream_t stream)
{
    (void)in_sizes; (void)n_in; (void)out_size;
    const float* x        = (const float*)d_in[0];
    const float* norm_w   = (const float*)d_in[1];
    const float* Win[2]   = {(const float*)d_in[2],  (const float*)d_in[10]};
    const float* convw[2] = {(const float*)d_in[3],  (const float*)d_in[11]};
    const float* convb[2] = {(const float*)d_in[4],  (const float*)d_in[12]};
    const float* dtbias[2]= {(const float*)d_in[5],  (const float*)d_in[13]};
    const float* Alog[2]  = {(const float*)d_in[6],  (const float*)d_in[14]};
    const float* Dsk[2]   = {(const float*)d_in[7],  (const float*)d_in[15]};
    const float* mnw[2]   = {(const float*)d_in[8],  (const float*)d_in[16]};
    const float* Wout[2]  = {(const float*)d_in[9],  (const float*)d_in[17]};
    const float* projW    = (const float*)d_in[18];
    const float* projb    = (const float*)d_in[19];
    float* out = (float*)d_out;

    const int M = B_ * L_;

    // ---- workspace layout (256B-aligned chunks), ~247 MB ----
    char* base = (char*)d_ws;
    size_t off = 0;
    #define WALLOC(name, type, count) \
        type* name = (type*)(base + off); off = (off + (size_t)(count) * sizeof(type) + 255) & ~(size_t)255;
    WALLOC(xnb,  unsigned short, (size_t)M * DM)       // bf16 normed input
    WALLOC(zx,   float,          (size_t)M * DIP)      // in_proj out (per dir)
    WALLOC(xs,   float,          (size_t)M * DI)
    WALLOC(bcb,  float,          (size_t)M * 2 * DS)
    WALLOC(dtb,  float,          (size_t)M * NH)
    WALLOC(dab,  float,          (size_t)M * NH)
    WALLOC(ysb,  float,          (size_t)M * DI)
    WALLOC(ub,   unsigned short, (size_t)M * DI)       // bf16 gated u
    WALLOC(dob,  float,          (size_t)M * DI)       // concat(y_fwd,y_bwd) f32
    WALLOC(dbb,  unsigned short, (size_t)M * DI)       // ^ bf16
    WALLOC(winb0, unsigned short, (size_t)NPAD * DM)
    WALLOC(winb1, unsigned short, (size_t)NPAD * DM)
    WALLOC(woutb0, unsigned short, (size_t)DM * DI)
    WALLOC(woutb1, unsigned short, (size_t)DM * DI)
    WALLOC(projwb, unsigned short, (size_t)DM * DI)
    #undef WALLOC
    if (off > ws_size) return;   // workspace too small: bail (visible as incorrect)

    unsigned short* winb[2]  = {winb0, winb1};
    unsigned short* woutb[2] = {woutb0, woutb1};

    // weight casts (W_in zero-padded 4384 -> 4480 rows)
    castpad_kernel<<<(NPAD * DM / 4 + 255) / 256, 256, 0, stream>>>(Win[0], winb0, DIP * DM, NPAD * DM);
    castpad_kernel<<<(NPAD * DM / 4 + 255) / 256, 256, 0, stream>>>(Win[1], winb1, DIP * DM, NPAD * DM);
    castpad_kernel<<<(DM * DI / 4 + 255) / 256, 256, 0, stream>>>(Wout[0], woutb0, DM * DI, DM * DI);
    castpad_kernel<<<(DM * DI / 4 + 255) / 256, 256, 0, stream>>>(Wout[1], woutb1, DM * DI, DM * DI);
    castpad_kernel<<<(DM * DI / 4 + 255) / 256, 256, 0, stream>>>(projW, projwb, DM * DI, DM * DI);

    rmsnorm_kernel<<<M, 256, 0, stream>>>(x, norm_w, xnb);

    for (int d = 0; d < 2; ++d) {
        gemm_bf16_kernel<<<dim3(NPAD / 128, M / 128), 256, 0, stream>>>(
            xnb, winb[d], zx, nullptr, nullptr, M, DIP, DM, DIP, 0, /*flipA=*/d, 0);
        convdt_kernel<<<M, 256, 0, stream>>>(zx, convw[d], convb[d], dtbias[d],
                                             Alog[d], Dsk[d], xs, bcb, dtb, dab, ysb);
        scan_kernel<<<dim3(64, 4), 256, 0, stream>>>(xs, bcb, dtb, dab, ysb);
        gate_kernel<<<M, 256, 0, stream>>>(ysb, zx, mnw[d], ub);
        gemm_bf16_kernel<<<dim3(DM / 128, M / 128), 256, 0, stream>>>(
            ub, woutb[d], dob, nullptr, nullptr, M, DM, DI, 2 * DM, d * DM, 0, /*flipOut=*/d);
    }
    castpad_kernel<<<(M * DI / 4 + 255) / 256, 256, 0, stream>>>(dob, dbb, M * DI, M * DI);
    gemm_bf16_kernel<<<dim3(DM / 128, M / 128), 256, 0, stream>>>(
        dbb, projwb, out, projb, x, M, DM, 2 * DM, DM, 0, 0, 0);
}

// Round 8
// 2022.616 us; speedup vs baseline: 1.4959x; 1.4959x over previous
//
#include <hip/hip_runtime.h>
#include <math.h>

#define B_ 2
#define L_ 2048
#define DM 1024
#define DS 128
#define DI 2048
#define NH 32
#define CONVD 2304
#define DIP 4384
#define NPAD 4480
#define EPS_ 1e-5f
#define Q_ 128
#define NC_ 16

typedef __attribute__((ext_vector_type(8))) short bf16x8;
typedef __attribute__((ext_vector_type(4))) float f32x4;

__device__ __forceinline__ float silu_f(float x) { return x / (1.0f + __expf(-x)); }

__device__ __forceinline__ unsigned short f2bf(float x) {
    union { float f; unsigned u; } v; v.f = x;
    unsigned r = v.u + 0x7fffu + ((v.u >> 16) & 1u);
    return (unsigned short)(r >> 16);
}

__device__ __forceinline__ void gload_lds16(const unsigned short* g, unsigned short* l) {
    __builtin_amdgcn_global_load_lds(
        (const __attribute__((address_space(1))) unsigned int*)g,
        (__attribute__((address_space(3))) unsigned int*)l, 16, 0, 0);
}

// ---------------- fp32 -> bf16 cast with optional zero tail-pad ----------------
__global__ __launch_bounds__(256) void castpad_kernel(
    const float* __restrict__ src, unsigned short* __restrict__ dst, int n_src, int n_dst)
{
    int i = (blockIdx.x * 256 + threadIdx.x) * 4;
    if (i >= n_dst) return;
    ushort4 o;
    if (i < n_src) {
        float4 v = *(const float4*)(src + i);
        o = make_ushort4(f2bf(v.x), f2bf(v.y), f2bf(v.z), f2bf(v.w));
    } else {
        o = make_ushort4(0, 0, 0, 0);
    }
    *(ushort4*)(dst + i) = o;
}

// ---------------- rmsnorm over 1024 cols, bf16 out ----------------
__global__ __launch_bounds__(256) void rmsnorm_kernel(
    const float* __restrict__ x, const float* __restrict__ w, unsigned short* __restrict__ out)
{
    int row = blockIdx.x;
    int t = threadIdx.x;
    const float4* xr = (const float4*)(x + (size_t)row * DM);
    float4 v = xr[t];
    float ss = v.x*v.x + v.y*v.y + v.z*v.z + v.w*v.w;
#pragma unroll
    for (int o = 32; o > 0; o >>= 1) ss += __shfl_down(ss, o, 64);
    __shared__ float red[4];
    if ((t & 63) == 0) red[t >> 6] = ss;
    __syncthreads();
    float tot = red[0] + red[1] + red[2] + red[3];
    float inv = rsqrtf(tot * (1.0f / DM) + EPS_);
    float4 wv = ((const float4*)w)[t];
    ushort4 o4 = make_ushort4(f2bf(v.x * inv * wv.x), f2bf(v.y * inv * wv.y),
                              f2bf(v.z * inv * wv.z), f2bf(v.w * inv * wv.w));
    ((ushort4*)(out + (size_t)row * DM))[t] = o4;
}

// ---------------- bf16 MFMA GEMM (m97 structure) ----------------
// Output: fp32 to C (with optional bias/resid), or bf16 to C16 if C16 != null.
__global__ __launch_bounds__(256, 2) void gemm_bf16_kernel(
    const unsigned short* __restrict__ A, const unsigned short* __restrict__ Wt,
    float* __restrict__ C, unsigned short* __restrict__ C16,
    const float* __restrict__ bias, const float* __restrict__ resid,
    int M, int N, int K, int ldc, int col_off, int flipA, int flipOut)
{
    __shared__ unsigned short As[128 * 32];
    __shared__ unsigned short Bs[128 * 32];
    const int tid = threadIdx.x;
    const int lane = tid & 63, wave = tid >> 6;
    const int wr = wave >> 1, wc = wave & 1;
    const int r16 = lane & 15, kg = lane >> 4;
    const int bn0 = blockIdx.x * 128;
    const int bm0 = blockIdx.y * 128;

    f32x4 acc[4][4];
#pragma unroll
    for (int m = 0; m < 4; ++m)
#pragma unroll
        for (int n = 0; n < 4; ++n) { f32x4 z = {0.f, 0.f, 0.f, 0.f}; acc[m][n] = z; }

    for (int k0 = 0; k0 < K; k0 += 32) {
#pragma unroll
        for (int i = 0; i < 2; ++i) {
            int c = wave * 128 + i * 64 + lane;
            int r = c >> 2;
            int kk = (c & 3) << 3;
            int gr = bm0 + r;
            if (flipA) gr ^= (L_ - 1);
            gload_lds16(A + (size_t)gr * K + k0 + kk, As + (size_t)(wave * 128 + i * 64) * 8);
            gload_lds16(Wt + (size_t)(bn0 + r) * K + k0 + kk, Bs + (size_t)(wave * 128 + i * 64) * 8);
        }
        __syncthreads();
        bf16x8 af[4], bfr[4];
        const bf16x8* Ap = (const bf16x8*)As;
        const bf16x8* Bp = (const bf16x8*)Bs;
#pragma unroll
        for (int m = 0; m < 4; ++m) af[m] = Ap[(wr * 64 + m * 16 + r16) * 4 + kg];
#pragma unroll
        for (int n = 0; n < 4; ++n) bfr[n] = Bp[(wc * 64 + n * 16 + r16) * 4 + kg];
#pragma unroll
        for (int m = 0; m < 4; ++m)
#pragma unroll
            for (int n = 0; n < 4; ++n)
                acc[m][n] = __builtin_amdgcn_mfma_f32_16x16x32_bf16(af[m], bfr[n], acc[m][n], 0, 0, 0);
        __syncthreads();
    }

#pragma unroll
    for (int m = 0; m < 4; ++m) {
        int row = bm0 + wr * 64 + m * 16 + kg * 4;
#pragma unroll
        for (int n = 0; n < 4; ++n) {
            int col = bn0 + wc * 64 + n * 16 + r16;
            if (col < N) {
                float bv = bias ? bias[col] : 0.f;
#pragma unroll
                for (int j = 0; j < 4; ++j) {
                    int ro = flipOut ? ((row + j) ^ (L_ - 1)) : (row + j);
                    size_t o = (size_t)ro * ldc + col_off + col;
                    float val = acc[m][n][j] + bv;
                    if (resid) val += resid[o];
                    if (C16) C16[o] = f2bf(val);
                    else     C[o] = val;
                }
            }
        }
    }
}

// ---------------- causal depthwise conv(4) + silu + dt / dt*A ----------------
__global__ __launch_bounds__(256) void convdt_kernel(
    const float* __restrict__ zx, const float* __restrict__ conv_w,
    const float* __restrict__ conv_b, const float* __restrict__ dt_bias,
    const float* __restrict__ A_log,
    float* __restrict__ xs, float* __restrict__ bc,
    float* __restrict__ dtb, float* __restrict__ dab)
{
    int row = blockIdx.x;          // b*L + l
    int l = row & (L_ - 1);
    int t = threadIdx.x;
#pragma unroll
    for (int cc = 0; cc < 9; ++cc) {
        int c = t + cc * 256;      // CONVD = 2304 = 9*256
        float acc = conv_b[c];
#pragma unroll
        for (int k = 0; k < 4; ++k) {
            int ll = l - 3 + k;
            if (ll >= 0)
                acc = fmaf(conv_w[c * 4 + k], zx[(size_t)(row - 3 + k) * DIP + DI + c], acc);
        }
        float v = silu_f(acc);
        if (c < DI) xs[(size_t)row * DI + c] = v;
        else        bc[(size_t)row * (2 * DS) + (c - DI)] = v;
    }
    if (t < NH) {
        float xv = zx[(size_t)row * DIP + DI + CONVD + t] + dt_bias[t];
        float dt = (xv > 20.f) ? xv : log1pf(__expf(xv));
        float a = -__expf(A_log[t]);
        dtb[row * NH + t] = dt;
        dab[row * NH + t] = dt * a;     // log-decay per step
    }
}

// ---------------- chunk A: local end-state  S_local[p][n] ----------------
// grid (64 bh, 16 chunks), 256 thr. scs[(bh*NC+c)*64*128 + p*128 + n]
__global__ __launch_bounds__(256) void chunk_state_kernel(
    const float* __restrict__ xs, const float* __restrict__ bc,
    const float* __restrict__ dtb, const float* __restrict__ dab,
    float* __restrict__ scs, float* __restrict__ la_sum)
{
    int bh = blockIdx.x, c = blockIdx.y;
    int b = bh >> 5, h = bh & 31;
    size_t base = (size_t)b * L_ + (size_t)c * Q_;
    int t = threadIdx.x;

    __shared__ float Bs[128 * 132];
    __shared__ float xl[128 * 64];
    __shared__ float la[128], w[128];

    if (t < 128) la[t] = dab[(base + t) * NH + h];
    __syncthreads();
#pragma unroll
    for (int off = 1; off < 128; off <<= 1) {
        float v = 0.f;
        if (t < 128 && t >= off) v = la[t - off];
        __syncthreads();
        if (t < 128) la[t] += v;
        __syncthreads();
    }
    float ltot = la[127];
    if (t < 128) w[t] = __expf(ltot - la[t]) * dtb[(base + t) * NH + h];
    if (t == 0) la_sum[bh * NC_ + c] = ltot;

#pragma unroll
    for (int i = 0; i < 8; ++i) {            // x chunk: 128x64
        int lin4 = i * 256 + t;
        int s = lin4 >> 4, p4 = (lin4 & 15) << 2;
        *(float4*)&xl[s * 64 + p4] = *(const float4*)&xs[(base + s) * DI + h * 64 + p4];
    }
#pragma unroll
    for (int i = 0; i < 16; ++i) {           // B chunk: 128x128, pitch 132
        int lin4 = i * 256 + t;
        int s = lin4 >> 5, n4 = (lin4 & 31) << 2;
        *(float4*)&Bs[s * 132 + n4] = *(const float4*)&bc[(base + s) * (2 * DS) + n4];
    }
    __syncthreads();

    int pg = t >> 5, ng = t & 31;            // p = pg*8+j, n = ng+32k
    float acc[8][4];
#pragma unroll
    for (int j = 0; j < 8; ++j)
#pragma unroll
        for (int k = 0; k < 4; ++k) acc[j][k] = 0.f;

    for (int s = 0; s < 128; ++s) {
        float ws = w[s];
        float4 xa = *(const float4*)&xl[s * 64 + pg * 8];
        float4 xb = *(const float4*)&xl[s * 64 + pg * 8 + 4];
        float xw[8] = {xa.x*ws, xa.y*ws, xa.z*ws, xa.w*ws, xb.x*ws, xb.y*ws, xb.z*ws, xb.w*ws};
#pragma unroll
        for (int k = 0; k < 4; ++k) {
            float bv = Bs[s * 132 + ng + 32 * k];
#pragma unroll
            for (int j = 0; j < 8; ++j) acc[j][k] = fmaf(xw[j], bv, acc[j][k]);
        }
    }
    float* outp = scs + (size_t)(bh * NC_ + c) * 64 * 128;
#pragma unroll
    for (int j = 0; j < 8; ++j)
#pragma unroll
        for (int k = 0; k < 4; ++k)
            outp[(pg * 8 + j) * 128 + ng + 32 * k] = acc[j][k];
}

// ---------------- chunk B: 16-step sequential combine (in-place start-state swap) ----
__global__ __launch_bounds__(256) void chunk_seq_kernel(
    float* __restrict__ scs, const float* __restrict__ la_sum)
{
    int bh = blockIdx.x, t = threadIdx.x;
    float S[32];
#pragma unroll
    for (int i = 0; i < 32; ++i) S[i] = 0.f;
    for (int c = 0; c < NC_; ++c) {
        float ef = __expf(la_sum[bh * NC_ + c]);
        float* p = scs + (size_t)(bh * NC_ + c) * 8192;
#pragma unroll
        for (int i = 0; i < 32; ++i) {
            int idx = i * 256 + t;
            float tmp = p[idx];
            p[idx] = S[i];               // store chunk START state
            S[i] = fmaf(S[i], ef, tmp);  // advance past this chunk
        }
    }
}

// ---------------- chunk C: y = scores@x + exp(la)*(C·S_in) + D*x ----------------
// grid (64 bh, 16 chunks), 256 thr.
__global__ __launch_bounds__(256) void chunk_out_kernel(
    const float* __restrict__ xs, const float* __restrict__ bc,
    const float* __restrict__ dtb, const float* __restrict__ dab,
    const float* __restrict__ scs, const float* __restrict__ Dskip,
    float* __restrict__ ys)
{
    int bh = blockIdx.x, c = blockIdx.y;
    int b = bh >> 5, h = bh & 31;
    size_t base = (size_t)b * L_ + (size_t)c * Q_;
    int t = threadIdx.x;

    __shared__ float sc[128 * 132];   // scores [s][t]; later aliased as Sin [n][p] pitch 65
    __shared__ float xl[128 * 64];
    __shared__ float tb[128 * 36];
    __shared__ float tc[128 * 36];
    __shared__ float la[128], dt[128];

    if (t < 128) {
        la[t] = dab[(base + t) * NH + h];
        dt[t] = dtb[(base + t) * NH + h];
    }
    __syncthreads();
#pragma unroll
    for (int off = 1; off < 128; off <<= 1) {
        float v = 0.f;
        if (t < 128 && t >= off) v = la[t - off];
        __syncthreads();
        if (t < 128) la[t] += v;
        __syncthreads();
    }
#pragma unroll
    for (int i = 0; i < 8; ++i) {            // stage x chunk
        int lin4 = i * 256 + t;
        int s = lin4 >> 4, p4 = (lin4 & 15) << 2;
        *(float4*)&xl[s * 64 + p4] = *(const float4*)&xs[(base + s) * DI + h * 64 + p4];
    }

    // ---- phase 1: scores_raw[t][s] = C_t . B_s  (contraction over n, 4 tiles) ----
    int ti = t >> 4, si = t & 15;            // row t = ti+16j, col s = si+16k
    float acc[8][8];
#pragma unroll
    for (int j = 0; j < 8; ++j)
#pragma unroll
        for (int k = 0; k < 8; ++k) acc[j][k] = 0.f;

    for (int n0 = 0; n0 < 128; n0 += 32) {
        __syncthreads();
#pragma unroll
        for (int i = 0; i < 4; ++i) {
            int lin4 = i * 256 + t;
            int s = lin4 >> 3, n4 = (lin4 & 7) << 2;
            *(float4*)&tb[s * 36 + n4] = *(const float4*)&bc[(base + s) * (2 * DS) + n0 + n4];
            *(float4*)&tc[s * 36 + n4] = *(const float4*)&bc[(base + s) * (2 * DS) + 128 + n0 + n4];
        }
        __syncthreads();
        for (int n = 0; n < 32; ++n) {
            float cv[8], bv[8];
#pragma unroll
            for (int j = 0; j < 8; ++j) cv[j] = tc[(ti + 16 * j) * 36 + n];
#pragma unroll
            for (int k = 0; k < 8; ++k) bv[k] = tb[(si + 16 * k) * 36 + n];
#pragma unroll
            for (int j = 0; j < 8; ++j)
#pragma unroll
                for (int k = 0; k < 8; ++k) acc[j][k] = fmaf(cv[j], bv[k], acc[j][k]);
        }
    }
    __syncthreads();

    // ---- phase 2: decay+mask+dt, write scores to LDS transposed [s][t] ----
#pragma unroll
    for (int j = 0; j < 8; ++j) {
        int tr = ti + 16 * j;
        float lat = la[tr];
#pragma unroll
        for (int k = 0; k < 8; ++k) {
            int sx = si + 16 * k;
            float v = 0.f;
            if (sx <= tr) v = acc[j][k] * __expf(lat - la[sx]) * dt[sx];
            sc[sx * 132 + tr] = v;
        }
    }
    __syncthreads();

    // ---- phase 4: y_intra[t][p] = sum_s scores[t][s] * x[s][p] ----
    int tg = t >> 3, pg = t & 7;             // row t = tg+32j, col p = pg*8+k
    float acc2[4][8];
#pragma unroll
    for (int j = 0; j < 4; ++j)
#pragma unroll
        for (int k = 0; k < 8; ++k) acc2[j][k] = 0.f;

    for (int s = 0; s < 128; ++s) {
        float scv[4];
#pragma unroll
        for (int j = 0; j < 4; ++j) scv[j] = sc[s * 132 + tg + 32 * j];
        float4 xa = *(const float4*)&xl[s * 64 + pg * 8];
        float4 xb = *(const float4*)&xl[s * 64 + pg * 8 + 4];
        float xv[8] = {xa.x, xa.y, xa.z, xa.w, xb.x, xb.y, xb.z, xb.w};
#pragma unroll
        for (int j = 0; j < 4; ++j)
#pragma unroll
            for (int k = 0; k < 8; ++k) acc2[j][k] = fmaf(scv[j], xv[k], acc2[j][k]);
    }
    __syncthreads();

    // ---- phase 5: y_inter = C_t . S_in  (S_in staged transposed [n][p] pitch 65) ----
    float* Sin = sc;                          // alias (scores dead)
    const float* sin_g = scs + (size_t)(bh * NC_ + c) * 8192;
#pragma unroll
    for (int i = 0; i < 32; ++i) {
        int lin = i * 256 + t;
        int p = lin >> 7, n = lin & 127;
        Sin[n * 65 + p] = sin_g[lin];
    }
    float acc3[4][8];
#pragma unroll
    for (int j = 0; j < 4; ++j)
#pragma unroll
        for (int k = 0; k < 8; ++k) acc3[j][k] = 0.f;

    for (int n0 = 0; n0 < 128; n0 += 32) {
        __syncthreads();
#pragma unroll
        for (int i = 0; i < 4; ++i) {
            int lin4 = i * 256 + t;
            int s = lin4 >> 3, n4 = (lin4 & 7) << 2;
            *(float4*)&tc[s * 36 + n4] = *(const float4*)&bc[(base + s) * (2 * DS) + 128 + n0 + n4];
        }
        __syncthreads();
        for (int n = 0; n < 32; ++n) {
            float cv[4];
#pragma unroll
            for (int j = 0; j < 4; ++j) cv[j] = tc[(tg + 32 * j) * 36 + n];
#pragma unroll
            for (int k = 0; k < 8; ++k) {
                float sv = Sin[(n0 + n) * 65 + pg * 8 + k];
#pragma unroll
                for (int j = 0; j < 4; ++j) acc3[j][k] = fmaf(cv[j], sv, acc3[j][k]);
            }
        }
    }

    // ---- combine + D-skip, write out ----
    float Dv = Dskip[h];
#pragma unroll
    for (int j = 0; j < 4; ++j) {
        int tr = tg + 32 * j;
        float Ej = __expf(la[tr]);
        float4 xa = *(const float4*)&xl[tr * 64 + pg * 8];
        float4 xb = *(const float4*)&xl[tr * 64 + pg * 8 + 4];
        float4 o0, o1;
        o0.x = acc2[j][0] + Ej * acc3[j][0] + Dv * xa.x;
        o0.y = acc2[j][1] + Ej * acc3[j][1] + Dv * xa.y;
        o0.z = acc2[j][2] + Ej * acc3[j][2] + Dv * xa.z;
        o0.w = acc2[j][3] + Ej * acc3[j][3] + Dv * xa.w;
        o1.x = acc2[j][4] + Ej * acc3[j][4] + Dv * xb.x;
        o1.y = acc2[j][5] + Ej * acc3[j][5] + Dv * xb.y;
        o1.z = acc2[j][6] + Ej * acc3[j][6] + Dv * xb.z;
        o1.w = acc2[j][7] + Ej * acc3[j][7] + Dv * xb.w;
        float* yp = ys + (base + tr) * DI + h * 64 + pg * 8;
        *(float4*)yp = o0;
        *(float4*)(yp + 4) = o1;
    }
}

// ---------------- gate: u = rmsnorm(y * silu(z)) * norm_w, bf16 out ----------------
__global__ __launch_bounds__(256) void gate_kernel(
    const float* __restrict__ ys, const float* __restrict__ zx,
    const float* __restrict__ nw, unsigned short* __restrict__ u)
{
    int row = blockIdx.x;
    int t = threadIdx.x;
    const float4* yr = (const float4*)(ys + (size_t)row * DI);
    const float4* zr = (const float4*)(zx + (size_t)row * DIP);
    float g[2][4];
    float ss = 0.f;
#pragma unroll
    for (int it = 0; it < 2; ++it) {
        int i = t + it * 256;
        float4 y4 = yr[i];
        float4 z4 = zr[i];
        float gv;
        gv = y4.x * silu_f(z4.x); g[it][0] = gv; ss += gv * gv;
        gv = y4.y * silu_f(z4.y); g[it][1] = gv; ss += gv * gv;
        gv = y4.z * silu_f(z4.z); g[it][2] = gv; ss += gv * gv;
        gv = y4.w * silu_f(z4.w); g[it][3] = gv; ss += gv * gv;
    }
#pragma unroll
    for (int o = 32; o > 0; o >>= 1) ss += __shfl_down(ss, o, 64);
    __shared__ float red[4];
    if ((t & 63) == 0) red[t >> 6] = ss;
    __syncthreads();
    float tot = red[0] + red[1] + red[2] + red[3];
    float inv = rsqrtf(tot * (1.0f / DI) + EPS_);
#pragma unroll
    for (int it = 0; it < 2; ++it) {
        int i = t + it * 256;
        float4 w4 = ((const float4*)nw)[i];
        ushort4 o4 = make_ushort4(f2bf(g[it][0] * inv * w4.x), f2bf(g[it][1] * inv * w4.y),
                                  f2bf(g[it][2] * inv * w4.z), f2bf(g[it][3] * inv * w4.w));
        ((ushort4*)(u + (size_t)row * DI))[i] = o4;
    }
}

extern "C" void kernel_launch(void* const* d_in, const int* in_sizes, int n_in,
                              void* d_out, int out_size, void* d_ws, size_t ws_size,
                              hipStream_t stream)
{
    (void)in_sizes; (void)n_in; (void)out_size;
    const float* x        = (const float*)d_in[0];
    const float* norm_w   = (const float*)d_in[1];
    const float* Win[2]   = {(const float*)d_in[2],  (const float*)d_in[10]};
    const float* convw[2] = {(const float*)d_in[3],  (const float*)d_in[11]};
    const float* convb[2] = {(const float*)d_in[4],  (const float*)d_in[12]};
    const float* dtbias[2]= {(const float*)d_in[5],  (const float*)d_in[13]};
    const float* Alog[2]  = {(const float*)d_in[6],  (const float*)d_in[14]};
    const float* Dsk[2]   = {(const float*)d_in[7],  (const float*)d_in[15]};
    const float* mnw[2]   = {(const float*)d_in[8],  (const float*)d_in[16]};
    const float* Wout[2]  = {(const float*)d_in[9],  (const float*)d_in[17]};
    const float* projW    = (const float*)d_in[18];
    const float* projb    = (const float*)d_in[19];
    float* out = (float*)d_out;

    const int M = B_ * L_;

    // ---- workspace layout (256B-aligned), ~239 MiB total (== proven round-1 footprint) ----
    char* base = (char*)d_ws;
    size_t off = 0;
    #define WALLOC(name, type, count) \
        type* name = (type*)(base + off); off = (off + (size_t)(count) * sizeof(type) + 255) & ~(size_t)255;
    WALLOC(xnb,  unsigned short, (size_t)M * DM)
    WALLOC(zx,   float,          (size_t)M * DIP)
    WALLOC(xs,   float,          (size_t)M * DI)
    WALLOC(bcb,  float,          (size_t)M * 2 * DS)
    WALLOC(dtb,  float,          (size_t)M * NH)
    WALLOC(dab,  float,          (size_t)M * NH)
    WALLOC(ysb,  float,          (size_t)M * DI)
    WALLOC(ub,   unsigned short, (size_t)M * DI)
    WALLOC(dbb,  unsigned short, (size_t)M * DI)       // concat(y_fwd,y_bwd) bf16 (direct epilogue)
    WALLOC(scs,  float,          (size_t)64 * NC_ * 64 * 128)   // chunk states (32 MB)
    WALLOC(lasum, float,         (size_t)64 * NC_)
    WALLOC(winb0, unsigned short, (size_t)NPAD * DM)
    WALLOC(winb1, unsigned short, (size_t)NPAD * DM)
    WALLOC(woutb0, unsigned short, (size_t)DM * DI)
    WALLOC(woutb1, unsigned short, (size_t)DM * DI)
    WALLOC(projwb, unsigned short, (size_t)DM * DI)
    #undef WALLOC
    if (off > ws_size) return;

    unsigned short* winb[2]  = {winb0, winb1};
    unsigned short* woutb[2] = {woutb0, woutb1};

    castpad_kernel<<<(NPAD * DM / 4 + 255) / 256, 256, 0, stream>>>(Win[0], winb0, DIP * DM, NPAD * DM);
    castpad_kernel<<<(NPAD * DM / 4 + 255) / 256, 256, 0, stream>>>(Win[1], winb1, DIP * DM, NPAD * DM);
    castpad_kernel<<<(DM * DI / 4 + 255) / 256, 256, 0, stream>>>(Wout[0], woutb0, DM * DI, DM * DI);
    castpad_kernel<<<(DM * DI / 4 + 255) / 256, 256, 0, stream>>>(Wout[1], woutb1, DM * DI, DM * DI);
    castpad_kernel<<<(DM * DI / 4 + 255) / 256, 256, 0, stream>>>(projW, projwb, DM * DI, DM * DI);

    rmsnorm_kernel<<<M, 256, 0, stream>>>(x, norm_w, xnb);

    for (int d = 0; d < 2; ++d) {
        gemm_bf16_kernel<<<dim3(NPAD / 128, M / 128), 256, 0, stream>>>(
            xnb, winb[d], zx, nullptr, nullptr, nullptr, M, DIP, DM, DIP, 0, /*flipA=*/d, 0);
        convdt_kernel<<<M, 256, 0, stream>>>(zx, convw[d], convb[d], dtbias[d],
                                             Alog[d], xs, bcb, dtb, dab);
        chunk_state_kernel<<<dim3(64, NC_), 256, 0, stream>>>(xs, bcb, dtb, dab, scs, lasum);
        chunk_seq_kernel<<<64, 256, 0, stream>>>(scs, lasum);
        chunk_out_kernel<<<dim3(64, NC_), 256, 0, stream>>>(xs, bcb, dtb, dab, scs, Dsk[d], ysb);
        gate_kernel<<<M, 256, 0, stream>>>(ysb, zx, mnw[d], ub);
        gemm_bf16_kernel<<<dim3(DM / 128, M / 128), 256, 0, stream>>>(
            ub, woutb[d], nullptr, dbb, nullptr, nullptr, M, DM, DI, 2 * DM, d * DM, 0, /*flipOut=*/d);
    }
    gemm_bf16_kernel<<<dim3(DM / 128, M / 128), 256, 0, stream>>>(
        dbb, projwb, out, nullptr, projb, x, M, DM, 2 * DM, DM, 0, 0, 0);
}

// Round 9
// 768.916 us; speedup vs baseline: 3.9350x; 2.6305x over previous
//
#include <hip/hip_runtime.h>
#include <math.h>

#define B_ 2
#define L_ 2048
#define DM 1024
#define DS 128
#define DI 2048
#define NH 32
#define CONVD 2304
#define DIP 4384
#define NPAD 4480
#define EPS_ 1e-5f
#define Q_ 128
#define NC_ 16
#define PT 136   // bf16 LDS pitch: multiple of 8 (16B-aligned rows), odd/32 bank spread

typedef __attribute__((ext_vector_type(8))) short bf16x8;
typedef __attribute__((ext_vector_type(4))) float f32x4;

__device__ __forceinline__ float silu_f(float x) { return x / (1.0f + __expf(-x)); }

__device__ __forceinline__ unsigned short f2bf(float x) {
    union { float f; unsigned u; } v; v.f = x;
    unsigned r = v.u + 0x7fffu + ((v.u >> 16) & 1u);
    return (unsigned short)(r >> 16);
}
__device__ __forceinline__ float bf2f(unsigned short s) {
    union { unsigned u; float f; } v; v.u = ((unsigned)s) << 16; return v.f;
}

__device__ __forceinline__ void gload_lds16(const unsigned short* g, unsigned short* l) {
    __builtin_amdgcn_global_load_lds(
        (const __attribute__((address_space(1))) unsigned int*)g,
        (__attribute__((address_space(3))) unsigned int*)l, 16, 0, 0);
}

// ---------------- fp32 -> bf16 cast with optional zero tail-pad ----------------
__global__ __launch_bounds__(256) void castpad_kernel(
    const float* __restrict__ src, unsigned short* __restrict__ dst, int n_src, int n_dst)
{
    int i = (blockIdx.x * 256 + threadIdx.x) * 4;
    if (i >= n_dst) return;
    ushort4 o;
    if (i < n_src) {
        float4 v = *(const float4*)(src + i);
        o = make_ushort4(f2bf(v.x), f2bf(v.y), f2bf(v.z), f2bf(v.w));
    } else {
        o = make_ushort4(0, 0, 0, 0);
    }
    *(ushort4*)(dst + i) = o;
}

// ---------------- rmsnorm over 1024 cols, bf16 out ----------------
__global__ __launch_bounds__(256) void rmsnorm_kernel(
    const float* __restrict__ x, const float* __restrict__ w, unsigned short* __restrict__ out)
{
    int row = blockIdx.x;
    int t = threadIdx.x;
    const float4* xr = (const float4*)(x + (size_t)row * DM);
    float4 v = xr[t];
    float ss = v.x*v.x + v.y*v.y + v.z*v.z + v.w*v.w;
#pragma unroll
    for (int o = 32; o > 0; o >>= 1) ss += __shfl_down(ss, o, 64);
    __shared__ float red[4];
    if ((t & 63) == 0) red[t >> 6] = ss;
    __syncthreads();
    float tot = red[0] + red[1] + red[2] + red[3];
    float inv = rsqrtf(tot * (1.0f / DM) + EPS_);
    float4 wv = ((const float4*)w)[t];
    ushort4 o4 = make_ushort4(f2bf(v.x * inv * wv.x), f2bf(v.y * inv * wv.y),
                              f2bf(v.z * inv * wv.z), f2bf(v.w * inv * wv.w));
    ((ushort4*)(out + (size_t)row * DM))[t] = o4;
}

// ---------------- bf16 MFMA GEMM (m97 structure) ----------------
__global__ __launch_bounds__(256, 2) void gemm_bf16_kernel(
    const unsigned short* __restrict__ A, const unsigned short* __restrict__ Wt,
    float* __restrict__ C, unsigned short* __restrict__ C16,
    const float* __restrict__ bias, const float* __restrict__ resid,
    int M, int N, int K, int ldc, int col_off, int flipA, int flipOut)
{
    __shared__ unsigned short As[128 * 32];
    __shared__ unsigned short Bs[128 * 32];
    const int tid = threadIdx.x;
    const int lane = tid & 63, wave = tid >> 6;
    const int wr = wave >> 1, wc = wave & 1;
    const int r16 = lane & 15, kg = lane >> 4;
    const int bn0 = blockIdx.x * 128;
    const int bm0 = blockIdx.y * 128;

    f32x4 acc[4][4];
#pragma unroll
    for (int m = 0; m < 4; ++m)
#pragma unroll
        for (int n = 0; n < 4; ++n) { f32x4 z = {0.f, 0.f, 0.f, 0.f}; acc[m][n] = z; }

    for (int k0 = 0; k0 < K; k0 += 32) {
#pragma unroll
        for (int i = 0; i < 2; ++i) {
            int c = wave * 128 + i * 64 + lane;
            int r = c >> 2;
            int kk = (c & 3) << 3;
            int gr = bm0 + r;
            if (flipA) gr ^= (L_ - 1);
            gload_lds16(A + (size_t)gr * K + k0 + kk, As + (size_t)(wave * 128 + i * 64) * 8);
            gload_lds16(Wt + (size_t)(bn0 + r) * K + k0 + kk, Bs + (size_t)(wave * 128 + i * 64) * 8);
        }
        __syncthreads();
        bf16x8 af[4], bfr[4];
        const bf16x8* Ap = (const bf16x8*)As;
        const bf16x8* Bp = (const bf16x8*)Bs;
#pragma unroll
        for (int m = 0; m < 4; ++m) af[m] = Ap[(wr * 64 + m * 16 + r16) * 4 + kg];
#pragma unroll
        for (int n = 0; n < 4; ++n) bfr[n] = Bp[(wc * 64 + n * 16 + r16) * 4 + kg];
#pragma unroll
        for (int m = 0; m < 4; ++m)
#pragma unroll
            for (int n = 0; n < 4; ++n)
                acc[m][n] = __builtin_amdgcn_mfma_f32_16x16x32_bf16(af[m], bfr[n], acc[m][n], 0, 0, 0);
        __syncthreads();
    }

#pragma unroll
    for (int m = 0; m < 4; ++m) {
        int row = bm0 + wr * 64 + m * 16 + kg * 4;
#pragma unroll
        for (int n = 0; n < 4; ++n) {
            int col = bn0 + wc * 64 + n * 16 + r16;
            if (col < N) {
                float bv = bias ? bias[col] : 0.f;
#pragma unroll
                for (int j = 0; j < 4; ++j) {
                    int ro = flipOut ? ((row + j) ^ (L_ - 1)) : (row + j);
                    size_t o = (size_t)ro * ldc + col_off + col;
                    float val = acc[m][n][j] + bv;
                    if (resid) val += resid[o];
                    if (C16) C16[o] = f2bf(val);
                    else     C[o] = val;
                }
            }
        }
    }
}

// ---------------- causal depthwise conv(4) + silu + dt / dt*A ----------------
__global__ __launch_bounds__(256) void convdt_kernel(
    const float* __restrict__ zx, const float* __restrict__ conv_w,
    const float* __restrict__ conv_b, const float* __restrict__ dt_bias,
    const float* __restrict__ A_log,
    float* __restrict__ xs, float* __restrict__ bc,
    float* __restrict__ dtb, float* __restrict__ dab)
{
    int row = blockIdx.x;          // b*L + l
    int l = row & (L_ - 1);
    int t = threadIdx.x;
#pragma unroll
    for (int cc = 0; cc < 9; ++cc) {
        int c = t + cc * 256;      // CONVD = 2304 = 9*256
        float acc = conv_b[c];
#pragma unroll
        for (int k = 0; k < 4; ++k) {
            int ll = l - 3 + k;
            if (ll >= 0)
                acc = fmaf(conv_w[c * 4 + k], zx[(size_t)(row - 3 + k) * DIP + DI + c], acc);
        }
        float v = silu_f(acc);
        if (c < DI) xs[(size_t)row * DI + c] = v;
        else        bc[(size_t)row * (2 * DS) + (c - DI)] = v;
    }
    if (t < NH) {
        float xv = zx[(size_t)row * DIP + DI + CONVD + t] + dt_bias[t];
        float dt = (xv > 20.f) ? xv : log1pf(__expf(xv));
        float a = -__expf(A_log[t]);
        dtb[row * NH + t] = dt;
        dab[row * NH + t] = dt * a;     // log-decay per step
    }
}

// ---------------- chunk A (MFMA): S_local[p][n] = sum_s (w_s x[s][p]) B[s][n] ----------
// grid (64 bh, 16 chunks), 256 thr / 4 waves. K=s=128 via 16x16x32 bf16 MFMA.
// Operands staged TRANSPOSED (contraction must be the fast axis): xwT[64][PT], BT[128][PT].
__global__ __launch_bounds__(256) void chunk_state_kernel(
    const float* __restrict__ xs, const float* __restrict__ bc,
    const float* __restrict__ dtb, const float* __restrict__ dab,
    float* __restrict__ scs, float* __restrict__ la_sum)
{
    int bh = blockIdx.x, c = blockIdx.y;
    int b = bh >> 5, h = bh & 31;
    size_t base = (size_t)b * L_ + (size_t)c * Q_;
    int t = threadIdx.x;
    const int lane = t & 63, wave = t >> 6;
    const int r16 = lane & 15, kg = lane >> 4;
    const int wr = wave >> 1, wc = wave & 1;   // p-half (32), n-half (64)

    __shared__ unsigned short xwT[64 * PT];    // [p][s]
    __shared__ unsigned short BT[128 * PT];    // [n][s]
    __shared__ float la[128], w[128];

    if (t < 128) la[t] = dab[(base + t) * NH + h];
    __syncthreads();
#pragma unroll
    for (int off = 1; off < 128; off <<= 1) {
        float v = 0.f;
        if (t < 128 && t >= off) v = la[t - off];
        __syncthreads();
        if (t < 128) la[t] += v;
        __syncthreads();
    }
    float ltot = la[127];
    if (t < 128) w[t] = __expf(ltot - la[t]) * dtb[(base + t) * NH + h];
    if (t == 0) la_sum[bh * NC_ + c] = ltot;
    __syncthreads();

    // stage xwT (transposed, w-scaled) and BT (transposed)
#pragma unroll
    for (int i = 0; i < 8; ++i) {              // x: 128 s x 64 p
        int lin4 = i * 256 + t;
        int s = lin4 >> 4, p4 = (lin4 & 15) << 2;
        float4 xv = *(const float4*)&xs[(base + s) * DI + h * 64 + p4];
        float ws = w[s];
        xwT[(p4 + 0) * PT + s] = f2bf(xv.x * ws);
        xwT[(p4 + 1) * PT + s] = f2bf(xv.y * ws);
        xwT[(p4 + 2) * PT + s] = f2bf(xv.z * ws);
        xwT[(p4 + 3) * PT + s] = f2bf(xv.w * ws);
    }
#pragma unroll
    for (int i = 0; i < 16; ++i) {             // B: 128 s x 128 n
        int lin4 = i * 256 + t;
        int s = lin4 >> 5, n4 = (lin4 & 31) << 2;
        float4 bv = *(const float4*)&bc[(base + s) * (2 * DS) + n4];
        BT[(n4 + 0) * PT + s] = f2bf(bv.x);
        BT[(n4 + 1) * PT + s] = f2bf(bv.y);
        BT[(n4 + 2) * PT + s] = f2bf(bv.z);
        BT[(n4 + 3) * PT + s] = f2bf(bv.w);
    }
    __syncthreads();

    f32x4 acc[2][4];
#pragma unroll
    for (int m = 0; m < 2; ++m)
#pragma unroll
        for (int n = 0; n < 4; ++n) { f32x4 z = {0.f, 0.f, 0.f, 0.f}; acc[m][n] = z; }

#pragma unroll
    for (int ks = 0; ks < 4; ++ks) {
        bf16x8 af[2], bfr[4];
#pragma unroll
        for (int m = 0; m < 2; ++m)
            af[m] = *(const bf16x8*)&xwT[(wr * 32 + m * 16 + r16) * PT + ks * 32 + kg * 8];
#pragma unroll
        for (int n = 0; n < 4; ++n)
            bfr[n] = *(const bf16x8*)&BT[(wc * 64 + n * 16 + r16) * PT + ks * 32 + kg * 8];
#pragma unroll
        for (int m = 0; m < 2; ++m)
#pragma unroll
            for (int n = 0; n < 4; ++n)
                acc[m][n] = __builtin_amdgcn_mfma_f32_16x16x32_bf16(af[m], bfr[n], acc[m][n], 0, 0, 0);
    }

    float* outp = scs + (size_t)(bh * NC_ + c) * 8192;
#pragma unroll
    for (int m = 0; m < 2; ++m) {
        int p0 = wr * 32 + m * 16 + kg * 4;
#pragma unroll
        for (int n = 0; n < 4; ++n) {
            int nn = wc * 64 + n * 16 + r16;
#pragma unroll
            for (int j = 0; j < 4; ++j)
                outp[(p0 + j) * 128 + nn] = acc[m][n][j];
        }
    }
}

// ---------------- chunk B: 16-step sequential combine (in-place start-state swap) ----
__global__ __launch_bounds__(256) void chunk_seq_kernel(
    float* __restrict__ scs, const float* __restrict__ la_sum)
{
    int bh = blockIdx.x, t = threadIdx.x;
    float S[32];
#pragma unroll
    for (int i = 0; i < 32; ++i) S[i] = 0.f;
    for (int c = 0; c < NC_; ++c) {
        float ef = __expf(la_sum[bh * NC_ + c]);
        float* p = scs + (size_t)(bh * NC_ + c) * 8192;
#pragma unroll
        for (int i = 0; i < 32; ++i) {
            int idx = i * 256 + t;
            float tmp = p[idx];
            p[idx] = S[i];               // store chunk START state
            S[i] = fmaf(S[i], ef, tmp);  // advance past this chunk
        }
    }
}

// ---------------- chunk C (MFMA): y = decayed(C.B^T) @ x + exp(la)*(C @ S_in^T) + D*x --
// grid (64 bh, 16 chunks), 256 thr / 4 waves.
// GEMM1: scores[t][s] = C_t . B_s (K=n=128). Decay+mask in regs -> sc bf16 (reuses Bb).
// GEMM2: acc = C @ Sin (K=n); acc *= exp(la_t); acc += sc @ xT (K=s). +D*x, store.
// scs layout [p][n] is already the transposed B-operand for GEMM2a (no transpose needed).
__global__ __launch_bounds__(256) void chunk_out_kernel(
    const float* __restrict__ xs, const float* __restrict__ bc,
    const float* __restrict__ dtb, const float* __restrict__ dab,
    const float* __restrict__ scs, const float* __restrict__ Dskip,
    float* __restrict__ ys)
{
    int bh = blockIdx.x, c = blockIdx.y;
    int b = bh >> 5, h = bh & 31;
    size_t base = (size_t)b * L_ + (size_t)c * Q_;
    int t = threadIdx.x;
    const int lane = t & 63, wave = t >> 6;
    const int r16 = lane & 15, kg = lane >> 4;

    __shared__ unsigned short Cb[128 * PT];    // [t][n]
    __shared__ unsigned short Bb[128 * PT];    // [s][n]; reused as sc[t][s] after GEMM1
    __shared__ unsigned short xTb[64 * PT];    // [p][s]
    __shared__ unsigned short Sinb[64 * PT];   // [p][n]  (from scs[p][n], direct copy)
    __shared__ float la[128], dt[128];

    if (t < 128) {
        la[t] = dab[(base + t) * NH + h];
        dt[t] = dtb[(base + t) * NH + h];
    }
    __syncthreads();
#pragma unroll
    for (int off = 1; off < 128; off <<= 1) {
        float v = 0.f;
        if (t < 128 && t >= off) v = la[t - off];
        __syncthreads();
        if (t < 128) la[t] += v;
        __syncthreads();
    }

    // ---- stage all operands ----
#pragma unroll
    for (int i = 0; i < 16; ++i) {             // B,C: 128 s|t x 128 n
        int lin4 = i * 256 + t;
        int s = lin4 >> 5, n4 = (lin4 & 31) << 2;
        float4 bv = *(const float4*)&bc[(base + s) * (2 * DS) + n4];
        float4 cv = *(const float4*)&bc[(base + s) * (2 * DS) + 128 + n4];
        *(ushort4*)&Bb[s * PT + n4] = make_ushort4(f2bf(bv.x), f2bf(bv.y), f2bf(bv.z), f2bf(bv.w));
        *(ushort4*)&Cb[s * PT + n4] = make_ushort4(f2bf(cv.x), f2bf(cv.y), f2bf(cv.z), f2bf(cv.w));
    }
#pragma unroll
    for (int i = 0; i < 8; ++i) {              // x: 128 s x 64 p (transposed store)
        int lin4 = i * 256 + t;
        int s = lin4 >> 4, p4 = (lin4 & 15) << 2;
        float4 xv = *(const float4*)&xs[(base + s) * DI + h * 64 + p4];
        xTb[(p4 + 0) * PT + s] = f2bf(xv.x);
        xTb[(p4 + 1) * PT + s] = f2bf(xv.y);
        xTb[(p4 + 2) * PT + s] = f2bf(xv.z);
        xTb[(p4 + 3) * PT + s] = f2bf(xv.w);
    }
    {
        const float* sin_g = scs + (size_t)(bh * NC_ + c) * 8192;
#pragma unroll
        for (int i = 0; i < 8; ++i) {          // Sin: 64 p x 128 n (direct row copy)
            int lin4 = i * 256 + t;
            int p = lin4 >> 5, n4 = (lin4 & 31) << 2;
            float4 sv = *(const float4*)&sin_g[p * 128 + n4];
            *(ushort4*)&Sinb[p * PT + n4] = make_ushort4(f2bf(sv.x), f2bf(sv.y), f2bf(sv.z), f2bf(sv.w));
        }
    }
    __syncthreads();

    // ---- GEMM1: scores quadrant per wave; (wr=0,wc=1) is strictly upper -> all zero ----
    const int wr = wave >> 1, wc = wave & 1;   // t-half, s-half (64 each)
    f32x4 acc[4][4];
#pragma unroll
    for (int m = 0; m < 4; ++m)
#pragma unroll
        for (int n = 0; n < 4; ++n) { f32x4 z = {0.f, 0.f, 0.f, 0.f}; acc[m][n] = z; }
    const bool skipq = (wr == 0 && wc == 1);
    if (!skipq) {
#pragma unroll
        for (int ks = 0; ks < 4; ++ks) {
            bf16x8 af[4], bfr[4];
#pragma unroll
            for (int m = 0; m < 4; ++m)
                af[m] = *(const bf16x8*)&Cb[(wr * 64 + m * 16 + r16) * PT + ks * 32 + kg * 8];
#pragma unroll
            for (int n = 0; n < 4; ++n)
                bfr[n] = *(const bf16x8*)&Bb[(wc * 64 + n * 16 + r16) * PT + ks * 32 + kg * 8];
#pragma unroll
            for (int m = 0; m < 4; ++m)
#pragma unroll
                for (int n = 0; n < 4; ++n)
                    acc[m][n] = __builtin_amdgcn_mfma_f32_16x16x32_bf16(af[m], bfr[n], acc[m][n], 0, 0, 0);
        }
    }
    __syncthreads();   // all GEMM1 reads of Bb done before overwrite as sc

    // ---- decay+mask -> sc bf16 into Bb ----
#pragma unroll
    for (int m = 0; m < 4; ++m) {
        int t0 = wr * 64 + m * 16 + kg * 4;
#pragma unroll
        for (int n = 0; n < 4; ++n) {
            int sx = wc * 64 + n * 16 + r16;
            float las = la[sx], dts = dt[sx];
#pragma unroll
            for (int j = 0; j < 4; ++j) {
                int tr = t0 + j;
                float v = 0.f;
                if (!skipq && sx <= tr) v = acc[m][n][j] * __expf(la[tr] - las) * dts;
                Bb[tr * PT + sx] = f2bf(v);
            }
        }
    }

    // ---- GEMM2a: acc2 = C @ Sin^T (K=n=128); output 128t x 64p, wave quad 64x32 ----
    const int wr2 = wave >> 1, wc2 = wave & 1;
    f32x4 acc2[4][2];
#pragma unroll
    for (int m = 0; m < 4; ++m)
#pragma unroll
        for (int n = 0; n < 2; ++n) { f32x4 z = {0.f, 0.f, 0.f, 0.f}; acc2[m][n] = z; }
#pragma unroll
    for (int ks = 0; ks < 4; ++ks) {
        bf16x8 af[4], bfr[2];
#pragma unroll
        for (int m = 0; m < 4; ++m)
            af[m] = *(const bf16x8*)&Cb[(wr2 * 64 + m * 16 + r16) * PT + ks * 32 + kg * 8];
#pragma unroll
        for (int n = 0; n < 2; ++n)
            bfr[n] = *(const bf16x8*)&Sinb[(wc2 * 32 + n * 16 + r16) * PT + ks * 32 + kg * 8];
#pragma unroll
        for (int m = 0; m < 4; ++m)
#pragma unroll
            for (int n = 0; n < 2; ++n)
                acc2[m][n] = __builtin_amdgcn_mfma_f32_16x16x32_bf16(af[m], bfr[n], acc2[m][n], 0, 0, 0);
    }
    // scale inter-chunk term by exp(la_t)
#pragma unroll
    for (int m = 0; m < 4; ++m) {
        int t0 = wr2 * 64 + m * 16 + kg * 4;
#pragma unroll
        for (int j = 0; j < 4; ++j) {
            float e = __expf(la[t0 + j]);
#pragma unroll
            for (int n = 0; n < 2; ++n) acc2[m][n][j] *= e;
        }
    }
    __syncthreads();   // all sc writes visible before GEMM2b reads

    // ---- GEMM2b: acc2 += sc @ xT (K=s=128) ----
#pragma unroll
    for (int ks = 0; ks < 4; ++ks) {
        bf16x8 af[4], bfr[2];
#pragma unroll
        for (int m = 0; m < 4; ++m)
            af[m] = *(const bf16x8*)&Bb[(wr2 * 64 + m * 16 + r16) * PT + ks * 32 + kg * 8];
#pragma unroll
        for (int n = 0; n < 2; ++n)
            bfr[n] = *(const bf16x8*)&xTb[(wc2 * 32 + n * 16 + r16) * PT + ks * 32 + kg * 8];
#pragma unroll
        for (int m = 0; m < 4; ++m)
#pragma unroll
            for (int n = 0; n < 2; ++n)
                acc2[m][n] = __builtin_amdgcn_mfma_f32_16x16x32_bf16(af[m], bfr[n], acc2[m][n], 0, 0, 0);
    }

    // ---- epilogue: + D*x, store ys ----
    float Dv = Dskip[h];
#pragma unroll
    for (int m = 0; m < 4; ++m) {
        int t0 = wr2 * 64 + m * 16 + kg * 4;
#pragma unroll
        for (int n = 0; n < 2; ++n) {
            int p = wc2 * 32 + n * 16 + r16;
#pragma unroll
            for (int j = 0; j < 4; ++j) {
                int tr = t0 + j;
                float xv = bf2f(xTb[p * PT + tr]);
                ys[(base + tr) * DI + h * 64 + p] = acc2[m][n][j] + Dv * xv;
            }
        }
    }
}

// ---------------- gate: u = rmsnorm(y * silu(z)) * norm_w, bf16 out ----------------
__global__ __launch_bounds__(256) void gate_kernel(
    const float* __restrict__ ys, const float* __restrict__ zx,
    const float* __restrict__ nw, unsigned short* __restrict__ u)
{
    int row = blockIdx.x;
    int t = threadIdx.x;
    const float4* yr = (const float4*)(ys + (size_t)row * DI);
    const float4* zr = (const float4*)(zx + (size_t)row * DIP);
    float g[2][4];
    float ss = 0.f;
#pragma unroll
    for (int it = 0; it < 2; ++it) {
        int i = t + it * 256;
        float4 y4 = yr[i];
        float4 z4 = zr[i];
        float gv;
        gv = y4.x * silu_f(z4.x); g[it][0] = gv; ss += gv * gv;
        gv = y4.y * silu_f(z4.y); g[it][1] = gv; ss += gv * gv;
        gv = y4.z * silu_f(z4.z); g[it][2] = gv; ss += gv * gv;
        gv = y4.w * silu_f(z4.w); g[it][3] = gv; ss += gv * gv;
    }
#pragma unroll
    for (int o = 32; o > 0; o >>= 1) ss += __shfl_down(ss, o, 64);
    __shared__ float red[4];
    if ((t & 63) == 0) red[t >> 6] = ss;
    __syncthreads();
    float tot = red[0] + red[1] + red[2] + red[3];
    float inv = rsqrtf(tot * (1.0f / DI) + EPS_);
#pragma unroll
    for (int it = 0; it < 2; ++it) {
        int i = t + it * 256;
        float4 w4 = ((const float4*)nw)[i];
        ushort4 o4 = make_ushort4(f2bf(g[it][0] * inv * w4.x), f2bf(g[it][1] * inv * w4.y),
                                  f2bf(g[it][2] * inv * w4.z), f2bf(g[it][3] * inv * w4.w));
        ((ushort4*)(u + (size_t)row * DI))[i] = o4;
    }
}

extern "C" void kernel_launch(void* const* d_in, const int* in_sizes, int n_in,
                              void* d_out, int out_size, void* d_ws, size_t ws_size,
                              hipStream_t stream)
{
    (void)in_sizes; (void)n_in; (void)out_size;
    const float* x        = (const float*)d_in[0];
    const float* norm_w   = (const float*)d_in[1];
    const float* Win[2]   = {(const float*)d_in[2],  (const float*)d_in[10]};
    const float* convw[2] = {(const float*)d_in[3],  (const float*)d_in[11]};
    const float* convb[2] = {(const float*)d_in[4],  (const float*)d_in[12]};
    const float* dtbias[2]= {(const float*)d_in[5],  (const float*)d_in[13]};
    const float* Alog[2]  = {(const float*)d_in[6],  (const float*)d_in[14]};
    const float* Dsk[2]   = {(const float*)d_in[7],  (const float*)d_in[15]};
    const float* mnw[2]   = {(const float*)d_in[8],  (const float*)d_in[16]};
    const float* Wout[2]  = {(const float*)d_in[9],  (const float*)d_in[17]};
    const float* projW    = (const float*)d_in[18];
    const float* projb    = (const float*)d_in[19];
    float* out = (float*)d_out;

    const int M = B_ * L_;

    // ---- workspace layout (256B-aligned), ~239 MiB total (proven fit) ----
    char* base = (char*)d_ws;
    size_t off = 0;
    #define WALLOC(name, type, count) \
        type* name = (type*)(base + off); off = (off + (size_t)(count) * sizeof(type) + 255) & ~(size_t)255;
    WALLOC(xnb,  unsigned short, (size_t)M * DM)
    WALLOC(zx,   float,          (size_t)M * DIP)
    WALLOC(xs,   float,          (size_t)M * DI)
    WALLOC(bcb,  float,          (size_t)M * 2 * DS)
    WALLOC(dtb,  float,          (size_t)M * NH)
    WALLOC(dab,  float,          (size_t)M * NH)
    WALLOC(ysb,  float,          (size_t)M * DI)
    WALLOC(ub,   unsigned short, (size_t)M * DI)
    WALLOC(dbb,  unsigned short, (size_t)M * DI)
    WALLOC(scs,  float,          (size_t)64 * NC_ * 64 * 128)
    WALLOC(lasum, float,         (size_t)64 * NC_)
    WALLOC(winb0, unsigned short, (size_t)NPAD * DM)
    WALLOC(winb1, unsigned short, (size_t)NPAD * DM)
    WALLOC(woutb0, unsigned short, (size_t)DM * DI)
    WALLOC(woutb1, unsigned short, (size_t)DM * DI)
    WALLOC(projwb, unsigned short, (size_t)DM * DI)
    #undef WALLOC
    if (off > ws_size) return;

    unsigned short* winb[2]  = {winb0, winb1};
    unsigned short* woutb[2] = {woutb0, woutb1};

    castpad_kernel<<<(NPAD * DM / 4 + 255) / 256, 256, 0, stream>>>(Win[0], winb0, DIP * DM, NPAD * DM);
    castpad_kernel<<<(NPAD * DM / 4 + 255) / 256, 256, 0, stream>>>(Win[1], winb1, DIP * DM, NPAD * DM);
    castpad_kernel<<<(DM * DI / 4 + 255) / 256, 256, 0, stream>>>(Wout[0], woutb0, DM * DI, DM * DI);
    castpad_kernel<<<(DM * DI / 4 + 255) / 256, 256, 0, stream>>>(Wout[1], woutb1, DM * DI, DM * DI);
    castpad_kernel<<<(DM * DI / 4 + 255) / 256, 256, 0, stream>>>(projW, projwb, DM * DI, DM * DI);

    rmsnorm_kernel<<<M, 256, 0, stream>>>(x, norm_w, xnb);

    for (int d = 0; d < 2; ++d) {
        gemm_bf16_kernel<<<dim3(NPAD / 128, M / 128), 256, 0, stream>>>(
            xnb, winb[d], zx, nullptr, nullptr, nullptr, M, DIP, DM, DIP, 0, /*flipA=*/d, 0);
        convdt_kernel<<<M, 256, 0, stream>>>(zx, convw[d], convb[d], dtbias[d],
                                             Alog[d], xs, bcb, dtb, dab);
        chunk_state_kernel<<<dim3(64, NC_), 256, 0, stream>>>(xs, bcb, dtb, dab, scs, lasum);
        chunk_seq_kernel<<<64, 256, 0, stream>>>(scs, lasum);
        chunk_out_kernel<<<dim3(64, NC_), 256, 0, stream>>>(xs, bcb, dtb, dab, scs, Dsk[d], ysb);
        gate_kernel<<<M, 256, 0, stream>>>(ysb, zx, mnw[d], ub);
        gemm_bf16_kernel<<<dim3(DM / 128, M / 128), 256, 0, stream>>>(
            ub, woutb[d], nullptr, dbb, nullptr, nullptr, M, DM, DI, 2 * DM, d * DM, 0, /*flipOut=*/d);
    }
    gemm_bf16_kernel<<<dim3(DM / 128, M / 128), 256, 0, stream>>>(
        dbb, projwb, out, nullptr, projb, x, M, DM, 2 * DM, DM, 0, 0, 0);
}

// Round 12
// 708.214 us; speedup vs baseline: 4.2722x; 1.0857x over previous
//
#include <hip/hip_runtime.h>
#include <math.h>

#define B_ 2
#define L_ 2048
#define DM 1024
#define DS 128
#define DI 2048
#define NH 32
#define CONVD 2304
#define DIP 4384
#define NPAD 4480
#define DTOFF 4352   // DI + CONVD: dt columns start here
#define EPS_ 1e-5f
#define Q_ 128
#define NC_ 16
#define PT 136       // bf16 LDS pitch

typedef __attribute__((ext_vector_type(8))) short bf16x8;
typedef __attribute__((ext_vector_type(4))) float f32x4;

__device__ __forceinline__ float silu_f(float x) { return x / (1.0f + __expf(-x)); }

__device__ __forceinline__ unsigned short f2bf(float x) {
    union { float f; unsigned u; } v; v.f = x;
    unsigned r = v.u + 0x7fffu + ((v.u >> 16) & 1u);
    return (unsigned short)(r >> 16);
}
__device__ __forceinline__ float bf2f(unsigned short s) {
    union { unsigned u; float f; } v; v.u = ((unsigned)s) << 16; return v.f;
}

__device__ __forceinline__ void gload_lds16(const unsigned short* g, unsigned short* l) {
    __builtin_amdgcn_global_load_lds(
        (const __attribute__((address_space(1))) unsigned int*)g,
        (__attribute__((address_space(3))) unsigned int*)l, 16, 0, 0);
}

// ---------------- fp32 -> bf16 cast with optional zero tail-pad ----------------
__global__ __launch_bounds__(256) void castpad_kernel(
    const float* __restrict__ src, unsigned short* __restrict__ dst, int n_src, int n_dst)
{
    int i = (blockIdx.x * 256 + threadIdx.x) * 4;
    if (i >= n_dst) return;
    ushort4 o;
    if (i < n_src) {
        float4 v = *(const float4*)(src + i);
        o = make_ushort4(f2bf(v.x), f2bf(v.y), f2bf(v.z), f2bf(v.w));
    } else {
        o = make_ushort4(0, 0, 0, 0);
    }
    *(ushort4*)(dst + i) = o;
}

// ---------------- rmsnorm over 1024 cols, bf16 out ----------------
__global__ __launch_bounds__(256) void rmsnorm_kernel(
    const float* __restrict__ x, const float* __restrict__ w, unsigned short* __restrict__ out)
{
    int row = blockIdx.x;
    int t = threadIdx.x;
    const float4* xr = (const float4*)(x + (size_t)row * DM);
    float4 v = xr[t];
    float ss = v.x*v.x + v.y*v.y + v.z*v.z + v.w*v.w;
#pragma unroll
    for (int o = 32; o > 0; o >>= 1) ss += __shfl_down(ss, o, 64);
    __shared__ float red[4];
    if ((t & 63) == 0) red[t >> 6] = ss;
    __syncthreads();
    float tot = red[0] + red[1] + red[2] + red[3];
    float inv = rsqrtf(tot * (1.0f / DM) + EPS_);
    float4 wv = ((const float4*)w)[t];
    ushort4 o4 = make_ushort4(f2bf(v.x * inv * wv.x), f2bf(v.y * inv * wv.y),
                              f2bf(v.z * inv * wv.z), f2bf(v.w * inv * wv.w));
    ((ushort4*)(out + (size_t)row * DM))[t] = o4;
}

// ---------------- bf16 MFMA GEMM (m97 structure + k-slice LDS swizzle + XCD swizzle) --
// Output modes: fp32 C (bias/resid), or bf16 C16; with C16, cols >= DTOFF spill fp32
// to Cdt (M x NH) when Cdt != null (keeps the dt path fp32).
__global__ __launch_bounds__(256, 2) void gemm_bf16_kernel(
    const unsigned short* __restrict__ A, const unsigned short* __restrict__ Wt,
    float* __restrict__ C, unsigned short* __restrict__ C16, float* __restrict__ Cdt,
    const float* __restrict__ bias, const float* __restrict__ resid,
    int M, int N, int K, int ldc, int col_off, int flipA, int flipOut)
{
    __shared__ unsigned short As[128 * 32];
    __shared__ unsigned short Bs[128 * 32];
    const int tid = threadIdx.x;
    const int lane = tid & 63, wave = tid >> 6;
    const int wr = wave >> 1, wc = wave & 1;
    const int r16 = lane & 15, kg = lane >> 4;

    // XCD-chunked block swizzle (all grids have nwg % 8 == 0)
    const int gx = gridDim.x;
    const int nwg = gx * gridDim.y;
    const int wg = blockIdx.y * gx + blockIdx.x;
    const int swzg = (wg & 7) * (nwg >> 3) + (wg >> 3);
    const int bn0 = (swzg % gx) * 128;
    const int bm0 = (swzg / gx) * 128;

    f32x4 acc[4][4];
#pragma unroll
    for (int m = 0; m < 4; ++m)
#pragma unroll
        for (int n = 0; n < 4; ++n) { f32x4 z = {0.f, 0.f, 0.f, 0.f}; acc[m][n] = z; }

    const int kswz = kg ^ ((r16 >> 1) & 3);   // content-addressed k-slice (bank de-conflict)

    for (int k0 = 0; k0 < K; k0 += 32) {
#pragma unroll
        for (int i = 0; i < 2; ++i) {
            int c = wave * 128 + i * 64 + lane;
            int r = c >> 2;
            int ks = c & 3;
            int ksrc = (ks ^ ((r >> 1) & 3)) << 3;   // pre-swizzle global source
            int gr = bm0 + r;
            if (flipA) gr ^= (L_ - 1);
            gload_lds16(A + (size_t)gr * K + k0 + ksrc, As + (size_t)(wave * 128 + i * 64) * 8);
            gload_lds16(Wt + (size_t)(bn0 + r) * K + k0 + ksrc, Bs + (size_t)(wave * 128 + i * 64) * 8);
        }
        __syncthreads();
        bf16x8 af[4], bfr[4];
        const bf16x8* Ap = (const bf16x8*)As;
        const bf16x8* Bp = (const bf16x8*)Bs;
#pragma unroll
        for (int m = 0; m < 4; ++m) af[m] = Ap[(wr * 64 + m * 16 + r16) * 4 + kswz];
#pragma unroll
        for (int n = 0; n < 4; ++n) bfr[n] = Bp[(wc * 64 + n * 16 + r16) * 4 + kswz];
#pragma unroll
        for (int m = 0; m < 4; ++m)
#pragma unroll
            for (int n = 0; n < 4; ++n)
                acc[m][n] = __builtin_amdgcn_mfma_f32_16x16x32_bf16(af[m], bfr[n], acc[m][n], 0, 0, 0);
        __syncthreads();
    }

#pragma unroll
    for (int m = 0; m < 4; ++m) {
        int row = bm0 + wr * 64 + m * 16 + kg * 4;
#pragma unroll
        for (int n = 0; n < 4; ++n) {
            int col = bn0 + wc * 64 + n * 16 + r16;
            if (col < N) {
                float bv = bias ? bias[col] : 0.f;
#pragma unroll
                for (int j = 0; j < 4; ++j) {
                    int ro = flipOut ? ((row + j) ^ (L_ - 1)) : (row + j);
                    size_t o = (size_t)ro * ldc + col_off + col;
                    float val = acc[m][n][j] + bv;
                    if (resid) val += resid[o];
                    if (C16) {
                        if (Cdt && col >= DTOFF) Cdt[(size_t)ro * NH + (col - DTOFF)] = val;
                        else                     C16[o] = f2bf(val);
                    } else {
                        C[o] = val;
                    }
                }
            }
        }
    }
}

// ---------------- causal depthwise conv(4) + silu, halo-tiled rolling history --------
// grid (9 col-blocks x 64 row-tiles), 256 thr; each thread owns 1 col, walks 64 rows.
__global__ __launch_bounds__(256) void convdt_kernel(
    const unsigned short* __restrict__ zxb, const float* __restrict__ conv_w,
    const float* __restrict__ conv_b,
    unsigned short* __restrict__ xs16, unsigned short* __restrict__ bc16)
{
    int c = blockIdx.x * 256 + threadIdx.x;   // 0..2303 (block-uniform xs/bc split: 2048=8*256)
    int r0 = blockIdx.y * 64;
    float w0 = conv_w[c * 4 + 0], w1 = conv_w[c * 4 + 1];
    float w2 = conv_w[c * 4 + 2], w3 = conv_w[c * 4 + 3];
    float bcv = conv_b[c];
    const unsigned short* src = zxb + DI + c;

    float h0 = 0.f, h1 = 0.f, h2 = 0.f;       // in[l-3], in[l-2], in[l-1]
    int l0 = r0 & (L_ - 1);
    if (l0 >= 3) h0 = bf2f(src[(size_t)(r0 - 3) * DIP]);
    if (l0 >= 2) h1 = bf2f(src[(size_t)(r0 - 2) * DIP]);
    if (l0 >= 1) h2 = bf2f(src[(size_t)(r0 - 1) * DIP]);

    for (int j = 0; j < 64; ++j) {
        size_t row = (size_t)(r0 + j);
        float cur = bf2f(src[row * DIP]);
        float a = fmaf(w0, h0, fmaf(w1, h1, fmaf(w2, h2, fmaf(w3, cur, bcv))));
        float v = silu_f(a);
        if (c < DI) xs16[row * DI + c] = f2bf(v);
        else        bc16[row * (2 * DS) + (c - DI)] = f2bf(v);
        h0 = h1; h1 = h2; h2 = cur;
    }
}

// ---------------- dt / dA from fp32 dtraw ----------------
__global__ __launch_bounds__(256) void dt_kernel(
    const float* __restrict__ dtraw, const float* __restrict__ dt_bias,
    const float* __restrict__ A_log, float* __restrict__ dtb, float* __restrict__ dab)
{
    int idx = blockIdx.x * 256 + threadIdx.x;  // M*NH
    int hh = idx & (NH - 1);
    float xv = dtraw[idx] + dt_bias[hh];
    float dt = (xv > 20.f) ? xv : log1pf(__expf(xv));
    float a = -__expf(A_log[hh]);
    dtb[idx] = dt;
    dab[idx] = dt * a;
}

// ---------------- chunk A (MFMA): S_local[p][n] = sum_s (w_s x[s][p]) B[s][n] --------
__global__ __launch_bounds__(256) void chunk_state_kernel(
    const unsigned short* __restrict__ xs16, const unsigned short* __restrict__ bc16,
    const float* __restrict__ dtb, const float* __restrict__ dab,
    float* __restrict__ scs, float* __restrict__ la_sum)
{
    int bh = blockIdx.x, c = blockIdx.y;
    int b = bh >> 5, h = bh & 31;
    size_t base = (size_t)b * L_ + (size_t)c * Q_;
    int t = threadIdx.x;
    const int lane = t & 63, wave = t >> 6;
    const int r16 = lane & 15, kg = lane >> 4;
    const int wr = wave >> 1, wc = wave & 1;

    __shared__ unsigned short xwT[64 * PT];    // [p][s]
    __shared__ unsigned short BT[128 * PT];    // [n][s]
    __shared__ float la[128], w[128];

    if (t < 128) la[t] = dab[(base + t) * NH + h];
    __syncthreads();
#pragma unroll
    for (int off = 1; off < 128; off <<= 1) {
        float v = 0.f;
        if (t < 128 && t >= off) v = la[t - off];
        __syncthreads();
        if (t < 128) la[t] += v;
        __syncthreads();
    }
    float ltot = la[127];
    if (t < 128) w[t] = __expf(ltot - la[t]) * dtb[(base + t) * NH + h];
    if (t == 0) la_sum[bh * NC_ + c] = ltot;
    __syncthreads();

#pragma unroll
    for (int i = 0; i < 4; ++i) {              // x: 128 s x 64 p bf16, transpose+scale
        int lin = i * 256 + t;
        int s = lin >> 3, p8 = (lin & 7) << 3;
        bf16x8 v = *(const bf16x8*)&xs16[(base + s) * DI + h * 64 + p8];
        float ws = w[s];
#pragma unroll
        for (int j = 0; j < 8; ++j)
            xwT[(p8 + j) * PT + s] = f2bf(bf2f((unsigned short)v[j]) * ws);
    }
#pragma unroll
    for (int i = 0; i < 8; ++i) {              // B: 128 s x 128 n bf16, transpose
        int lin = i * 256 + t;
        int s = lin >> 4, n8 = (lin & 15) << 3;
        bf16x8 v = *(const bf16x8*)&bc16[(base + s) * (2 * DS) + n8];
#pragma unroll
        for (int j = 0; j < 8; ++j)
            BT[(n8 + j) * PT + s] = (unsigned short)v[j];
    }
    __syncthreads();

    f32x4 acc[2][4];
#pragma unroll
    for (int m = 0; m < 2; ++m)
#pragma unroll
        for (int n = 0; n < 4; ++n) { f32x4 z = {0.f, 0.f, 0.f, 0.f}; acc[m][n] = z; }

#pragma unroll
    for (int ks = 0; ks < 4; ++ks) {
        bf16x8 af[2], bfr[4];
#pragma unroll
        for (int m = 0; m < 2; ++m)
            af[m] = *(const bf16x8*)&xwT[(wr * 32 + m * 16 + r16) * PT + ks * 32 + kg * 8];
#pragma unroll
        for (int n = 0; n < 4; ++n)
            bfr[n] = *(const bf16x8*)&BT[(wc * 64 + n * 16 + r16) * PT + ks * 32 + kg * 8];
#pragma unroll
        for (int m = 0; m < 2; ++m)
#pragma unroll
            for (int n = 0; n < 4; ++n)
                acc[m][n] = __builtin_amdgcn_mfma_f32_16x16x32_bf16(af[m], bfr[n], acc[m][n], 0, 0, 0);
    }

    float* outp = scs + (size_t)(bh * NC_ + c) * 8192;
#pragma unroll
    for (int m = 0; m < 2; ++m) {
        int p0 = wr * 32 + m * 16 + kg * 4;
#pragma unroll
        for (int n = 0; n < 4; ++n) {
            int nn = wc * 64 + n * 16 + r16;
#pragma unroll
            for (int j = 0; j < 4; ++j)
                outp[(p0 + j) * 128 + nn] = acc[m][n][j];
        }
    }
}

// ---------------- chunk B: 16-step sequential combine (in-place start-state swap) ----
__global__ __launch_bounds__(256) void chunk_seq_kernel(
    float* __restrict__ scs, const float* __restrict__ la_sum)
{
    int bh = blockIdx.x, t = threadIdx.x;
    float S[32];
#pragma unroll
    for (int i = 0; i < 32; ++i) S[i] = 0.f;
    for (int c = 0; c < NC_; ++c) {
        float ef = __expf(la_sum[bh * NC_ + c]);
        float* p = scs + (size_t)(bh * NC_ + c) * 8192;
#pragma unroll
        for (int i = 0; i < 32; ++i) {
            int idx = i * 256 + t;
            float tmp = p[idx];
            p[idx] = S[i];
            S[i] = fmaf(S[i], ef, tmp);
        }
    }
}

// ---------------- chunk C (MFMA): y = decayed(C.B^T)@x + exp(la)*(C@Sin^T) + D*x ------
__global__ __launch_bounds__(256) void chunk_out_kernel(
    const unsigned short* __restrict__ xs16, const unsigned short* __restrict__ bc16,
    const float* __restrict__ dtb, const float* __restrict__ dab,
    const float* __restrict__ scs, const float* __restrict__ Dskip,
    unsigned short* __restrict__ ys16)
{
    int bh = blockIdx.x, c = blockIdx.y;
    int b = bh >> 5, h = bh & 31;
    size_t base = (size_t)b * L_ + (size_t)c * Q_;
    int t = threadIdx.x;
    const int lane = t & 63, wave = t >> 6;
    const int r16 = lane & 15, kg = lane >> 4;

    __shared__ unsigned short Cb[128 * PT];    // [t][n]
    __shared__ unsigned short Bb[128 * PT];    // [s][n]; reused as sc[t][s]
    __shared__ unsigned short xTb[64 * PT];    // [p][s]
    __shared__ unsigned short Sinb[64 * PT];   // [p][n]
    __shared__ float la[128], dt[128];

    if (t < 128) {
        la[t] = dab[(base + t) * NH + h];
        dt[t] = dtb[(base + t) * NH + h];
    }
    __syncthreads();
#pragma unroll
    for (int off = 1; off < 128; off <<= 1) {
        float v = 0.f;
        if (t < 128 && t >= off) v = la[t - off];
        __syncthreads();
        if (t < 128) la[t] += v;
        __syncthreads();
    }

#pragma unroll
    for (int i = 0; i < 8; ++i) {              // B,C: direct bf16 row copies
        int lin = i * 256 + t;
        int s = lin >> 4, n8 = (lin & 15) << 3;
        *(bf16x8*)&Bb[s * PT + n8] = *(const bf16x8*)&bc16[(base + s) * (2 * DS) + n8];
        *(bf16x8*)&Cb[s * PT + n8] = *(const bf16x8*)&bc16[(base + s) * (2 * DS) + 128 + n8];
    }
#pragma unroll
    for (int i = 0; i < 4; ++i) {              // x: transpose bf16
        int lin = i * 256 + t;
        int s = lin >> 3, p8 = (lin & 7) << 3;
        bf16x8 v = *(const bf16x8*)&xs16[(base + s) * DI + h * 64 + p8];
#pragma unroll
        for (int j = 0; j < 8; ++j)
            xTb[(p8 + j) * PT + s] = (unsigned short)v[j];
    }
    {
        const float* sin_g = scs + (size_t)(bh * NC_ + c) * 8192;
#pragma unroll
        for (int i = 0; i < 8; ++i) {          // Sin: fp32 -> bf16 direct rows
            int lin4 = i * 256 + t;
            int p = lin4 >> 5, n4 = (lin4 & 31) << 2;
            float4 sv = *(const float4*)&sin_g[p * 128 + n4];
            *(ushort4*)&Sinb[p * PT + n4] = make_ushort4(f2bf(sv.x), f2bf(sv.y), f2bf(sv.z), f2bf(sv.w));
        }
    }
    __syncthreads();

    // ---- GEMM1: scores quadrant per wave; (wr=0,wc=1) strictly upper -> zero ----
    const int wr = wave >> 1, wc = wave & 1;
    f32x4 acc[4][4];
#pragma unroll
    for (int m = 0; m < 4; ++m)
#pragma unroll
        for (int n = 0; n < 4; ++n) { f32x4 z = {0.f, 0.f, 0.f, 0.f}; acc[m][n] = z; }
    const bool skipq = (wr == 0 && wc == 1);
    if (!skipq) {
#pragma unroll
        for (int ks = 0; ks < 4; ++ks) {
            bf16x8 af[4], bfr[4];
#pragma unroll
            for (int m = 0; m < 4; ++m)
                af[m] = *(const bf16x8*)&Cb[(wr * 64 + m * 16 + r16) * PT + ks * 32 + kg * 8];
#pragma unroll
            for (int n = 0; n < 4; ++n)
                bfr[n] = *(const bf16x8*)&Bb[(wc * 64 + n * 16 + r16) * PT + ks * 32 + kg * 8];
#pragma unroll
            for (int m = 0; m < 4; ++m)
#pragma unroll
                for (int n = 0; n < 4; ++n)
                    acc[m][n] = __builtin_amdgcn_mfma_f32_16x16x32_bf16(af[m], bfr[n], acc[m][n], 0, 0, 0);
        }
    }
    __syncthreads();

    // ---- decay+mask -> sc bf16 into Bb ----
#pragma unroll
    for (int m = 0; m < 4; ++m) {
        int t0 = wr * 64 + m * 16 + kg * 4;
#pragma unroll
        for (int n = 0; n < 4; ++n) {
            int sx = wc * 64 + n * 16 + r16;
            float las = la[sx], dts = dt[sx];
#pragma unroll
            for (int j = 0; j < 4; ++j) {
                int tr = t0 + j;
                float v = 0.f;
                if (!skipq && sx <= tr) v = acc[m][n][j] * __expf(la[tr] - las) * dts;
                Bb[tr * PT + sx] = f2bf(v);
            }
        }
    }

    // ---- GEMM2a: acc2 = C @ Sin^T; scale by exp(la_t) ----
    f32x4 acc2[4][2];
#pragma unroll
    for (int m = 0; m < 4; ++m)
#pragma unroll
        for (int n = 0; n < 2; ++n) { f32x4 z = {0.f, 0.f, 0.f, 0.f}; acc2[m][n] = z; }
#pragma unroll
    for (int ks = 0; ks < 4; ++ks) {
        bf16x8 af[4], bfr[2];
#pragma unroll
        for (int m = 0; m < 4; ++m)
            af[m] = *(const bf16x8*)&Cb[(wr * 64 + m * 16 + r16) * PT + ks * 32 + kg * 8];
#pragma unroll
        for (int n = 0; n < 2; ++n)
            bfr[n] = *(const bf16x8*)&Sinb[(wc * 32 + n * 16 + r16) * PT + ks * 32 + kg * 8];
#pragma unroll
        for (int m = 0; m < 4; ++m)
#pragma unroll
            for (int n = 0; n < 2; ++n)
                acc2[m][n] = __builtin_amdgcn_mfma_f32_16x16x32_bf16(af[m], bfr[n], acc2[m][n], 0, 0, 0);
    }
#pragma unroll
    for (int m = 0; m < 4; ++m) {
        int t0 = wr * 64 + m * 16 + kg * 4;
#pragma unroll
        for (int j = 0; j < 4; ++j) {
            float e = __expf(la[t0 + j]);
#pragma unroll
            for (int n = 0; n < 2; ++n) acc2[m][n][j] *= e;
        }
    }
    __syncthreads();

    // ---- GEMM2b: acc2 += sc @ xT ----
#pragma unroll
    for (int ks = 0; ks < 4; ++ks) {
        bf16x8 af[4], bfr[2];
#pragma unroll
        for (int m = 0; m < 4; ++m)
            af[m] = *(const bf16x8*)&Bb[(wr * 64 + m * 16 + r16) * PT + ks * 32 + kg * 8];
#pragma unroll
        for (int n = 0; n < 2; ++n)
            bfr[n] = *(const bf16x8*)&xTb[(wc * 32 + n * 16 + r16) * PT + ks * 32 + kg * 8];
#pragma unroll
        for (int m = 0; m < 4; ++m)
#pragma unroll
            for (int n = 0; n < 2; ++n)
                acc2[m][n] = __builtin_amdgcn_mfma_f32_16x16x32_bf16(af[m], bfr[n], acc2[m][n], 0, 0, 0);
    }

    // ---- epilogue: + D*x, bf16 store ----
    float Dv = Dskip[h];
#pragma unroll
    for (int m = 0; m < 4; ++m) {
        int t0 = wr * 64 + m * 16 + kg * 4;
#pragma unroll
        for (int n = 0; n < 2; ++n) {
            int p = wc * 32 + n * 16 + r16;
#pragma unroll
            for (int j = 0; j < 4; ++j) {
                int tr = t0 + j;
                float xv = bf2f(xTb[p * PT + tr]);
                ys16[(base + tr) * DI + h * 64 + p] = f2bf(acc2[m][n][j] + Dv * xv);
            }
        }
    }
}

// ---------------- gate: u = rmsnorm(y * silu(z)) * norm_w, bf16 in/out ----------------
__global__ __launch_bounds__(256) void gate_kernel(
    const unsigned short* __restrict__ ys16, const unsigned short* __restrict__ zxb,
    const float* __restrict__ nw, unsigned short* __restrict__ u)
{
    int row = blockIdx.x;
    int t = threadIdx.x;
    bf16x8 yv = *(const bf16x8*)&ys16[(size_t)row * DI + t * 8];
    bf16x8 zv = *(const bf16x8*)&zxb[(size_t)row * DIP + t * 8];   // z = cols [0,2048)
    float g[8];
    float ss = 0.f;
#pragma unroll
    for (int j = 0; j < 8; ++j) {
        float gv = bf2f((unsigned short)yv[j]) * silu_f(bf2f((unsigned short)zv[j]));
        g[j] = gv; ss += gv * gv;
    }
#pragma unroll
    for (int o = 32; o > 0; o >>= 1) ss += __shfl_down(ss, o, 64);
    __shared__ float red[4];
    if ((t & 63) == 0) red[t >> 6] = ss;
    __syncthreads();
    float tot = red[0] + red[1] + red[2] + red[3];
    float inv = rsqrtf(tot * (1.0f / DI) + EPS_);
    float4 w0 = *(const float4*)&nw[t * 8];
    float4 w1 = *(const float4*)&nw[t * 8 + 4];
    bf16x8 o8;
    o8[0] = (short)f2bf(g[0] * inv * w0.x); o8[1] = (short)f2bf(g[1] * inv * w0.y);
    o8[2] = (short)f2bf(g[2] * inv * w0.z); o8[3] = (short)f2bf(g[3] * inv * w0.w);
    o8[4] = (short)f2bf(g[4] * inv * w1.x); o8[5] = (short)f2bf(g[5] * inv * w1.y);
    o8[6] = (short)f2bf(g[6] * inv * w1.z); o8[7] = (short)f2bf(g[7] * inv * w1.w);
    *(bf16x8*)&u[(size_t)row * DI + t * 8] = o8;
}

extern "C" void kernel_launch(void* const* d_in, const int* in_sizes, int n_in,
                              void* d_out, int out_size, void* d_ws, size_t ws_size,
                              hipStream_t stream)
{
    (void)in_sizes; (void)n_in; (void)out_size;
    const float* x        = (const float*)d_in[0];
    const float* norm_w   = (const float*)d_in[1];
    const float* Win[2]   = {(const float*)d_in[2],  (const float*)d_in[10]};
    const float* convw[2] = {(const float*)d_in[3],  (const float*)d_in[11]};
    const float* convb[2] = {(const float*)d_in[4],  (const float*)d_in[12]};
    const float* dtbias[2]= {(const float*)d_in[5],  (const float*)d_in[13]};
    const float* Alog[2]  = {(const float*)d_in[6],  (const float*)d_in[14]};
    const float* Dsk[2]   = {(const float*)d_in[7],  (const float*)d_in[15]};
    const float* mnw[2]   = {(const float*)d_in[8],  (const float*)d_in[16]};
    const float* Wout[2]  = {(const float*)d_in[9],  (const float*)d_in[17]};
    const float* projW    = (const float*)d_in[18];
    const float* projb    = (const float*)d_in[19];
    float* out = (float*)d_out;

    const int M = B_ * L_;

    // ---- workspace layout (256B-aligned), ~193 MiB total ----
    char* base = (char*)d_ws;
    size_t off = 0;
    #define WALLOC(name, type, count) \
        type* name = (type*)(base + off); off = (off + (size_t)(count) * sizeof(type) + 255) & ~(size_t)255;
    WALLOC(xnb,   unsigned short, (size_t)M * DM)
    WALLOC(zxb,   unsigned short, (size_t)M * DIP)     // in_proj out, bf16
    WALLOC(dtraw, float,          (size_t)M * NH)      // dt cols fp32
    WALLOC(xs16,  unsigned short, (size_t)M * DI)
    WALLOC(bc16,  unsigned short, (size_t)M * 2 * DS)
    WALLOC(dtb,   float,          (size_t)M * NH)
    WALLOC(dab,   float,          (size_t)M * NH)
    WALLOC(ys16,  unsigned short, (size_t)M * DI)
    WALLOC(ub,    unsigned short, (size_t)M * DI)
    WALLOC(dbb,   unsigned short, (size_t)M * DI)
    WALLOC(scs,   float,          (size_t)64 * NC_ * 64 * 128)
    WALLOC(lasum, float,          (size_t)64 * NC_)
    WALLOC(winb0, unsigned short, (size_t)NPAD * DM)
    WALLOC(winb1, unsigned short, (size_t)NPAD * DM)
    WALLOC(woutb0, unsigned short, (size_t)DM * DI)
    WALLOC(woutb1, unsigned short, (size_t)DM * DI)
    WALLOC(projwb, unsigned short, (size_t)DM * DI)
    #undef WALLOC
    if (off > ws_size) return;

    unsigned short* winb[2]  = {winb0, winb1};
    unsigned short* woutb[2] = {woutb0, woutb1};

    castpad_kernel<<<(NPAD * DM / 4 + 255) / 256, 256, 0, stream>>>(Win[0], winb0, DIP * DM, NPAD * DM);
    castpad_kernel<<<(NPAD * DM / 4 + 255) / 256, 256, 0, stream>>>(Win[1], winb1, DIP * DM, NPAD * DM);
    castpad_kernel<<<(DM * DI / 4 + 255) / 256, 256, 0, stream>>>(Wout[0], woutb0, DM * DI, DM * DI);
    castpad_kernel<<<(DM * DI / 4 + 255) / 256, 256, 0, stream>>>(Wout[1], woutb1, DM * DI, DM * DI);
    castpad_kernel<<<(DM * DI / 4 + 255) / 256, 256, 0, stream>>>(projW, projwb, DM * DI, DM * DI);

    rmsnorm_kernel<<<M, 256, 0, stream>>>(x, norm_w, xnb);

    for (int d = 0; d < 2; ++d) {
        gemm_bf16_kernel<<<dim3(NPAD / 128, M / 128), 256, 0, stream>>>(
            xnb, winb[d], nullptr, zxb, dtraw, nullptr, nullptr,
            M, DIP, DM, DIP, 0, /*flipA=*/d, 0);
        convdt_kernel<<<dim3(9, M / 64), 256, 0, stream>>>(zxb, convw[d], convb[d], xs16, bc16);
        dt_kernel<<<M * NH / 256, 256, 0, stream>>>(dtraw, dtbias[d], Alog[d], dtb, dab);
        chunk_state_kernel<<<dim3(64, NC_), 256, 0, stream>>>(xs16, bc16, dtb, dab, scs, lasum);
        chunk_seq_kernel<<<64, 256, 0, stream>>>(scs, lasum);
        chunk_out_kernel<<<dim3(64, NC_), 256, 0, stream>>>(xs16, bc16, dtb, dab, scs, Dsk[d], ys16);
        gate_kernel<<<M, 256, 0, stream>>>(ys16, zxb, mnw[d], ub);
        gemm_bf16_kernel<<<dim3(DM / 128, M / 128), 256, 0, stream>>>(
            ub, woutb[d], nullptr, dbb, nullptr, nullptr, nullptr,
            M, DM, DI, 2 * DM, d * DM, 0, /*flipOut=*/d);
    }
    gemm_bf16_kernel<<<dim3(DM / 128, M / 128), 256, 0, stream>>>(
        dbb, projwb, out, nullptr, nullptr, projb, x, M, DM, 2 * DM, DM, 0, 0, 0);
}